// Round 1
// baseline (1818.945 us; speedup 1.0000x reference)
//
#include <hip/hip_runtime.h>

#define NP 4096
#define DIM 384
#define ML 65536
#define INFF 3.402823466e38f

typedef short bf16x8 __attribute__((ext_vector_type(8)));
typedef float f32x4 __attribute__((ext_vector_type(4)));
typedef unsigned short u16;
typedef unsigned long long u64;

typedef __attribute__((address_space(1))) unsigned int as1_u32;
typedef __attribute__((address_space(3))) unsigned int as3_u32;

__device__ __forceinline__ void gl_lds16(const void* g, void* l) {
  __builtin_amdgcn_global_load_lds((const as1_u32*)g, (as3_u32*)l, 16, 0, 0);
}

__device__ __forceinline__ u16 f2bf(float x) {
  unsigned u = __float_as_uint(x);
  u += 0x7FFFu + ((u >> 16) & 1u);
  return (u16)(u >> 16);
}

// ---------------- prep: fp32 -> bf16 copy + row sumsq ----------------
__global__ __launch_bounds__(128) void prep_kernel(const float* __restrict__ src,
                                                   u16* __restrict__ dst,
                                                   float* __restrict__ norms) {
  const int row = blockIdx.x;
  const int t = threadIdx.x;  // 128
  float s = 0.f;
  if (t < 96) {
    const float4 v = *reinterpret_cast<const float4*>(src + (size_t)row * DIM + t * 4);
    s = v.x * v.x + v.y * v.y + v.z * v.z + v.w * v.w;
    ushort4 u;
    u.x = f2bf(v.x); u.y = f2bf(v.y); u.z = f2bf(v.z); u.w = f2bf(v.w);
    *reinterpret_cast<ushort4*>(dst + (size_t)row * DIM + t * 4) = u;
  }
#pragma unroll
  for (int m = 1; m < 64; m <<= 1) s += __shfl_xor(s, m);
  __shared__ float red[2];
  if ((t & 63) == 0) red[t >> 6] = s;
  __syncthreads();
  if (t == 0) norms[row] = red[0] + red[1];
}

// ---------------- fused bf16 GEMM + row-min ----------------
__global__ __launch_bounds__(256) void gemm_min_kernel(const u16* __restrict__ Abf,
                                                       const u16* __restrict__ Bbf,
                                                       const float* __restrict__ a2,
                                                       const float* __restrict__ b2,
                                                       u64* __restrict__ packed) {
  __shared__ __align__(16) u16 As[128 * 64];
  __shared__ __align__(16) u16 Bs[128 * 64];
  const int tid = threadIdx.x;
  const int lane = tid & 63;
  const int w = tid >> 6;
  const int wr = w >> 1, wc = w & 1;
  const int n0 = blockIdx.y * 128;   // patch rows
  const int m0 = blockIdx.x * 128;   // lib rows (output cols)
  const int cl = lane & 15, rg = lane >> 4;

  f32x4 acc[4][4] = {};

  for (int kt = 0; kt < 6; ++kt) {
    const int k0 = kt * 64;
#pragma unroll
    for (int i = 0; i < 4; ++i) {
      const int b = i * 4096 + tid * 16;  // byte offset in 16KB tile
      const int r = b >> 7;               // /128B per row
      const int c = (b & 127) >> 1;       // ushort col
      gl_lds16(Abf + (size_t)(n0 + r) * DIM + k0 + c, (char*)As + b);
      gl_lds16(Bbf + (size_t)(m0 + r) * DIM + k0 + c, (char*)Bs + b);
    }
    __syncthreads();
#pragma unroll
    for (int kk = 0; kk < 2; ++kk) {
      bf16x8 af[4], bg[4];
      const int kof = kk * 32 + rg * 8;
#pragma unroll
      for (int f = 0; f < 4; ++f) {
        af[f] = *reinterpret_cast<const bf16x8*>(&As[(wr * 64 + f * 16 + cl) * 64 + kof]);
        bg[f] = *reinterpret_cast<const bf16x8*>(&Bs[(wc * 64 + f * 16 + cl) * 64 + kof]);
      }
#pragma unroll
      for (int i = 0; i < 4; ++i)
#pragma unroll
        for (int j = 0; j < 4; ++j)
          acc[i][j] = __builtin_amdgcn_mfma_f32_16x16x32_bf16(af[i], bg[j], acc[i][j], 0, 0, 0);
    }
    __syncthreads();
  }

  // epilogue: d2 = a2 + b2 - 2*dot ; per-row min over this block's 128 cols
  float bc[4];
#pragma unroll
  for (int fn = 0; fn < 4; ++fn) bc[fn] = b2[m0 + wc * 64 + fn * 16 + cl];

#pragma unroll
  for (int fm = 0; fm < 4; ++fm) {
#pragma unroll
    for (int j = 0; j < 4; ++j) {
      const int rowL = wr * 64 + fm * 16 + rg * 4 + j;  // C/D layout: col=lane&15, row=(lane>>4)*4+reg
      const float ar = a2[n0 + rowL];
      float best = INFF;
      int bidx = 0x7FFFFFFF;
#pragma unroll
      for (int fn = 0; fn < 4; ++fn) {
        const float d2 = ar + bc[fn] - 2.0f * acc[fm][fn][j];
        const int col = m0 + wc * 64 + fn * 16 + cl;
        if (d2 < best || (d2 == best && col < bidx)) { best = d2; bidx = col; }
      }
#pragma unroll
      for (int msk = 1; msk < 16; msk <<= 1) {
        const float ov = __shfl_xor(best, msk);
        const int oi = __shfl_xor(bidx, msk);
        if (ov < best || (ov == best && oi < bidx)) { best = ov; bidx = oi; }
      }
      if (cl == 0) {
        const u64 p = ((u64)__float_as_uint(fmaxf(best, 0.0f)) << 32) | (unsigned)bidx;
        atomicMin(&packed[n0 + rowL], p);
      }
    }
  }
}

// ---------------- candidate rows near the max ----------------
__global__ __launch_bounds__(256) void cand_kernel(const u64* __restrict__ packed,
                                                   int* __restrict__ cand) {
  const int tid = threadIdx.x;
  float mx = -1.f;
  for (int n = tid; n < NP; n += 256) {
    const float v = __uint_as_float((unsigned)(packed[n] >> 32));
    mx = fmaxf(mx, v);
  }
#pragma unroll
  for (int m = 1; m < 64; m <<= 1) mx = fmaxf(mx, __shfl_xor(mx, m));
  __shared__ float wmax[4];
  __shared__ float smax;
  if ((tid & 63) == 0) wmax[tid >> 6] = mx;
  __syncthreads();
  if (tid == 0) {
    smax = fmaxf(fmaxf(wmax[0], wmax[1]), fmaxf(wmax[2], wmax[3]));
    cand[0] = 0;
  }
  __syncthreads();
  const float thr = smax - 4.0f;  // margin in d^2: ~0.08 in d, >>, bf16 error
  for (int n = tid; n < NP; n += 256) {
    const float v = __uint_as_float((unsigned)(packed[n] >> 32));
    if (v >= thr) {
      const int slot = atomicAdd(&cand[0], 1);
      if (slot < 256) cand[1 + slot] = n;
    }
  }
}

// ---------------- exact fp32 refinement of candidate rows ----------------
__global__ __launch_bounds__(256) void refine_kernel(const float* __restrict__ patch,
                                                     const float* __restrict__ lib,
                                                     const int* __restrict__ cand,
                                                     u64* __restrict__ refined) {
  const int c = blockIdx.x;
  const int cnt = min(cand[0], 256);
  if (c >= cnt) return;
  const int chunk = blockIdx.y;  // 64 chunks x 1024 rows
  const int r = cand[1 + c];
  __shared__ float a[DIM];
  const int tid = threadIdx.x, lane = tid & 63, w = tid >> 6;
  for (int i = tid; i < DIM; i += 256) a[i] = patch[(size_t)r * DIM + i];
  __syncthreads();
  for (int it = 0; it < 256; ++it) {
    const int m = chunk * 1024 + w * 256 + it;
    const float* br = lib + (size_t)m * DIM;
    float s = 0.f;
#pragma unroll
    for (int k = 0; k < 6; ++k) {
      const float d = a[lane + k * 64] - br[lane + k * 64];
      s += d * d;
    }
#pragma unroll
    for (int msk = 1; msk < 64; msk <<= 1) s += __shfl_xor(s, msk);
    if (lane == 0) {
      const u64 p = ((u64)__float_as_uint(s) << 32) | (unsigned)m;
      atomicMin(&refined[c], p);
    }
  }
}

// ---------------- pick exact argmax row ----------------
__global__ __launch_bounds__(256) void pick_kernel(const u64* __restrict__ refined,
                                                   const int* __restrict__ cand,
                                                   int* __restrict__ scal_i,
                                                   float* __restrict__ scal_f) {
  const int tid = threadIdx.x, lane = tid & 63, w = tid >> 6;
  const int cnt = min(cand[0], 256);
  float v = -1.f;
  int nrow = 0x7FFFFFFF;
  int mi = 0;
  if (tid < cnt) {
    const u64 p = refined[tid];
    v = __uint_as_float((unsigned)(p >> 32));
    nrow = cand[1 + tid];
    mi = (int)(unsigned)p;
  }
#pragma unroll
  for (int msk = 1; msk < 64; msk <<= 1) {
    const float ov = __shfl_xor(v, msk);
    const int on = __shfl_xor(nrow, msk);
    const int om = __shfl_xor(mi, msk);
    if (ov > v || (ov == v && on < nrow)) { v = ov; nrow = on; mi = om; }
  }
  __shared__ float sv[4]; __shared__ int sn[4]; __shared__ int sm[4];
  if (lane == 0) { sv[w] = v; sn[w] = nrow; sm[w] = mi; }
  __syncthreads();
  if (tid == 0) {
    for (int k = 1; k < 4; ++k)
      if (sv[k] > v || (sv[k] == v && sn[k] < nrow)) { v = sv[k]; nrow = sn[k]; mi = sm[k]; }
    scal_i[0] = nrow;       // s_idx
    scal_i[1] = mi;         // m_star index
    scal_f[0] = sqrtf(fmaxf(v, 0.f));  // s_star
  }
}

// ---------------- w_dist: m_star vs whole lib (fp32 d^2) ----------------
__global__ __launch_bounds__(256) void wdist_kernel(const float* __restrict__ lib,
                                                    const int* __restrict__ scal_i,
                                                    float* __restrict__ wd) {
  __shared__ float a[DIM];
  const int tid = threadIdx.x, lane = tid & 63, w = tid >> 6;
  const int ms = scal_i[1];
  for (int i = tid; i < DIM; i += 256) a[i] = lib[(size_t)ms * DIM + i];
  __syncthreads();
  const int m = blockIdx.x * 4 + w;
  const float* br = lib + (size_t)m * DIM;
  float s = 0.f;
#pragma unroll
  for (int k = 0; k < 6; ++k) {
    const float d = a[lane + k * 64] - br[lane + k * 64];
    s += d * d;
  }
#pragma unroll
  for (int msk = 1; msk < 64; msk <<= 1) s += __shfl_xor(s, msk);
  if (lane == 0) wd[m] = s;
}

// ---------------- top-3 + final score ----------------
__device__ __forceinline__ bool lt2(float v, int i, float v2, int i2) {
  return v < v2 || (v == v2 && i < i2);
}
__device__ __forceinline__ void ins3(float v, int i, float* tv, int* ti) {
  if (lt2(v, i, tv[2], ti[2])) {
    tv[2] = v; ti[2] = i;
    if (lt2(tv[2], ti[2], tv[1], ti[1])) {
      float a = tv[1]; int b = ti[1]; tv[1] = tv[2]; ti[1] = ti[2]; tv[2] = a; ti[2] = b;
    }
    if (lt2(tv[1], ti[1], tv[0], ti[0])) {
      float a = tv[0]; int b = ti[0]; tv[0] = tv[1]; ti[0] = ti[1]; tv[1] = a; ti[1] = b;
    }
  }
}

__global__ __launch_bounds__(256) void final_kernel(const float* __restrict__ wd,
                                                    const float* __restrict__ patch,
                                                    const float* __restrict__ lib,
                                                    const int* __restrict__ scal_i,
                                                    const float* __restrict__ scal_f,
                                                    float* __restrict__ out) {
  const int tid = threadIdx.x, lane = tid & 63, w = tid >> 6;
  float tv[3] = {INFF, INFF, INFF};
  int ti[3] = {0x7FFFFFFF, 0x7FFFFFFF, 0x7FFFFFFF};
  for (int m = tid; m < ML; m += 256) ins3(wd[m], m, tv, ti);
#pragma unroll
  for (int msk = 1; msk < 64; msk <<= 1) {
    float ov[3]; int oi[3];
#pragma unroll
    for (int k = 0; k < 3; ++k) { ov[k] = __shfl_xor(tv[k], msk); oi[k] = __shfl_xor(ti[k], msk); }
#pragma unroll
    for (int k = 0; k < 3; ++k) ins3(ov[k], oi[k], tv, ti);
  }
  __shared__ float sv[12]; __shared__ int si[12];
  __shared__ int nn[2]; __shared__ float kk[2];
  if (lane == 0) {
#pragma unroll
    for (int k = 0; k < 3; ++k) { sv[w * 3 + k] = tv[k]; si[w * 3 + k] = ti[k]; }
  }
  __syncthreads();
  if (tid == 0) {
    float fv[3] = {INFF, INFF, INFF};
    int fi[3] = {0x7FFFFFFF, 0x7FFFFFFF, 0x7FFFFFFF};
    for (int k = 0; k < 12; ++k) ins3(sv[k], si[k], fv, fi);
    nn[0] = fi[1]; nn[1] = fi[2];  // skip nn[0] == m_star itself
  }
  __syncthreads();
  if (w < 2) {
    const int s_idx = scal_i[0];
    const int nnx = nn[w];
    float s = 0.f;
#pragma unroll
    for (int k = 0; k < 6; ++k) {
      const float d = patch[(size_t)s_idx * DIM + lane + k * 64] - lib[(size_t)nnx * DIM + lane + k * 64];
      s += d * d;
    }
#pragma unroll
    for (int msk = 1; msk < 64; msk <<= 1) s += __shfl_xor(s, msk);
    if (lane == 0) kk[w] = sqrtf(s);
  }
  __syncthreads();
  if (tid == 0) {
    const float s_star = scal_f[0];
    const float Ds = 19.59591794f;  // sqrt(384)
    const float wt = 1.0f - expf(s_star / Ds) / (expf(kk[0] / Ds) + expf(kk[1] / Ds));
    out[0] = wt * s_star;
  }
}

// ---------------- score map ----------------
__global__ __launch_bounds__(256) void minval_kernel(const u64* __restrict__ packed,
                                                     float* __restrict__ mv) {
  const int n = blockIdx.x * 256 + threadIdx.x;
  if (n < NP) mv[n] = sqrtf(fmaxf(__uint_as_float((unsigned)(packed[n] >> 32)), 0.f));
}

__global__ __launch_bounds__(256) void resize_kernel(const float* __restrict__ mv,
                                                     float* __restrict__ t1) {
  const int idx = blockIdx.x * 256 + threadIdx.x;  // 262144
  const int x = idx & 511, y = idx >> 9;
  const float sy = y * 0.125f - 0.4375f;
  const float sx = x * 0.125f - 0.4375f;
  const int y0 = (int)floorf(sy); const float fy = sy - (float)y0;
  const int x0 = (int)floorf(sx); const float fx = sx - (float)x0;
  const int ya = max(y0, 0), yb = min(y0 + 1, 63);
  const int xa = max(x0, 0), xb = min(x0 + 1, 63);
  const float v00 = mv[ya * 64 + xa], v01 = mv[ya * 64 + xb];
  const float v10 = mv[yb * 64 + xa], v11 = mv[yb * 64 + xb];
  t1[idx] = (1.f - fy) * ((1.f - fx) * v00 + fx * v01) + fy * ((1.f - fx) * v10 + fx * v11);
}

__device__ __constant__ float BW[9] = {
    0.0816741424f, 0.1016453893f, 0.1188358540f, 0.1305155396f, 0.1346581512f,
    0.1305155396f, 0.1188358540f, 0.1016453893f, 0.0816741424f};

__global__ __launch_bounds__(256) void blurv_kernel(const float* __restrict__ t1,
                                                    float* __restrict__ t2) {
  const int idx = blockIdx.x * 256 + threadIdx.x;
  const int x = idx & 511, y = idx >> 9;
  float s = 0.f;
#pragma unroll
  for (int k = -4; k <= 4; ++k) {
    const int yy = y + k;
    if (yy >= 0 && yy < 512) s += BW[k + 4] * t1[yy * 512 + x];
  }
  t2[idx] = s;
}

__global__ __launch_bounds__(256) void blurh_kernel(const float* __restrict__ t2,
                                                    float* __restrict__ out) {
  const int idx = blockIdx.x * 256 + threadIdx.x;
  const int x = idx & 511, y = idx >> 9;
  float s = 0.f;
#pragma unroll
  for (int k = -4; k <= 4; ++k) {
    const int xx = x + k;
    if (xx >= 0 && xx < 512) s += BW[k + 4] * t2[y * 512 + xx];
  }
  out[idx] = s;
}

extern "C" void kernel_launch(void* const* d_in, const int* in_sizes, int n_in,
                              void* d_out, int out_size, void* d_ws, size_t ws_size,
                              hipStream_t stream) {
  const float* patch = (const float*)d_in[0];
  const float* lib = (const float*)d_in[1];
  float* out = (float*)d_out;

  char* ws = (char*)d_ws;
  size_t off = 0;
  auto alloc = [&](size_t bytes) {
    void* p = ws + off;
    off += (bytes + 255) & ~(size_t)255;
    return p;
  };
  u16* Abf = (u16*)alloc((size_t)NP * DIM * 2);
  u16* Bbf = (u16*)alloc((size_t)ML * DIM * 2);
  float* a2 = (float*)alloc(NP * 4);
  float* b2 = (float*)alloc(ML * 4);
  u64* packed = (u64*)alloc(NP * 8);
  u64* refined = (u64*)alloc(256 * 8);
  int* cand = (int*)alloc(257 * 4);
  int* scal_i = (int*)alloc(64);
  float* scal_f = (float*)alloc(64);
  float* wd = (float*)alloc(ML * 4);
  float* mv = (float*)alloc(NP * 4);
  float* t1 = (float*)alloc(512 * 512 * 4);
  float* t2 = (float*)alloc(512 * 512 * 4);

  hipMemsetAsync(packed, 0xFF, NP * 8, stream);
  hipMemsetAsync(refined, 0xFF, 256 * 8, stream);

  prep_kernel<<<NP, 128, 0, stream>>>(patch, Abf, a2);
  prep_kernel<<<ML, 128, 0, stream>>>(lib, Bbf, b2);
  gemm_min_kernel<<<dim3(512, 32), 256, 0, stream>>>(Abf, Bbf, a2, b2, packed);
  cand_kernel<<<1, 256, 0, stream>>>(packed, cand);
  refine_kernel<<<dim3(256, 64), 256, 0, stream>>>(patch, lib, cand, refined);
  pick_kernel<<<1, 256, 0, stream>>>(refined, cand, scal_i, scal_f);
  wdist_kernel<<<ML / 4, 256, 0, stream>>>(lib, scal_i, wd);
  final_kernel<<<1, 256, 0, stream>>>(wd, patch, lib, scal_i, scal_f, out);
  minval_kernel<<<16, 256, 0, stream>>>(packed, mv);
  resize_kernel<<<1024, 256, 0, stream>>>(mv, t1);
  blurv_kernel<<<1024, 256, 0, stream>>>(t1, t2);
  blurh_kernel<<<1024, 256, 0, stream>>>(t2, out + 1);
}

// Round 2
// 1438.011 us; speedup vs baseline: 1.2649x; 1.2649x over previous
//
#include <hip/hip_runtime.h>

#define NP 4096
#define DIM 384
#define ML 65536
#define INFF 3.402823466e38f

typedef short bf16x8 __attribute__((ext_vector_type(8)));
typedef float f32x4 __attribute__((ext_vector_type(4)));
typedef unsigned short u16;
typedef unsigned long long u64;

typedef __attribute__((address_space(1))) unsigned int as1_u32;
typedef __attribute__((address_space(3))) unsigned int as3_u32;

__device__ __forceinline__ void gl_lds16(const void* g, void* l) {
  __builtin_amdgcn_global_load_lds((const as1_u32*)g, (as3_u32*)l, 16, 0, 0);
}

__device__ __forceinline__ u16 f2bf(float x) {
  unsigned u = __float_as_uint(x);
  u += 0x7FFFu + ((u >> 16) & 1u);
  return (u16)(u >> 16);
}

// ---------------- prep: fp32 -> bf16 copy + row sumsq ----------------
__global__ __launch_bounds__(128) void prep_kernel(const float* __restrict__ src,
                                                   u16* __restrict__ dst,
                                                   float* __restrict__ norms) {
  const int row = blockIdx.x;
  const int t = threadIdx.x;  // 128
  float s = 0.f;
  if (t < 96) {
    const float4 v = *reinterpret_cast<const float4*>(src + (size_t)row * DIM + t * 4);
    s = v.x * v.x + v.y * v.y + v.z * v.z + v.w * v.w;
    ushort4 u;
    u.x = f2bf(v.x); u.y = f2bf(v.y); u.z = f2bf(v.z); u.w = f2bf(v.w);
    *reinterpret_cast<ushort4*>(dst + (size_t)row * DIM + t * 4) = u;
  }
#pragma unroll
  for (int m = 1; m < 64; m <<= 1) s += __shfl_xor(s, m);
  __shared__ float red[2];
  if ((t & 63) == 0) red[t >> 6] = s;
  __syncthreads();
  if (t == 0) norms[row] = red[0] + red[1];
}

// ---------------- fused bf16 GEMM + row-min (T2 swizzle + T1 XCD remap) ----------------
__global__ __launch_bounds__(256) void gemm_min_kernel(const u16* __restrict__ Abf,
                                                       const u16* __restrict__ Bbf,
                                                       const float* __restrict__ a2,
                                                       const float* __restrict__ b2,
                                                       u64* __restrict__ packed) {
  __shared__ __align__(16) u16 As[128 * 64];
  __shared__ __align__(16) u16 Bs[128 * 64];
  const int tid = threadIdx.x;
  const int lane = tid & 63;
  const int w = tid >> 6;
  const int wr = w >> 1, wc = w & 1;

  // XCD-aware remap: nwg=16384 (divisible by 8). Each XCD gets a contiguous
  // logical chunk; logical low bits = patch tile so 32 consecutive blocks
  // share one B tile (L2 reuse), yt contiguous per XCD.
  const int orig = blockIdx.x;
  const int logical = (orig & 7) * 2048 + (orig >> 3);
  const int xt = logical & 31;
  const int yt = logical >> 5;
  const int n0 = xt * 128;   // patch rows
  const int m0 = yt * 128;   // lib rows (output cols)
  const int cl = lane & 15, rg = lane >> 4;

  f32x4 acc[4][4] = {};

  for (int kt = 0; kt < 6; ++kt) {
    const int k0 = kt * 64;
#pragma unroll
    for (int i = 0; i < 4; ++i) {
      const int P = i * 4096 + tid * 16;     // linear LDS dest byte
      const int r = P >> 7;                  // tile row (128B per row)
      const int L = P ^ ((r & 7) << 4);      // inverse-swizzled source offset
      const int c = (L & 127) >> 1;          // ushort col within row
      gl_lds16(Abf + (size_t)(n0 + r) * DIM + k0 + c, (char*)As + P);
      gl_lds16(Bbf + (size_t)(m0 + r) * DIM + k0 + c, (char*)Bs + P);
    }
    __syncthreads();
#pragma unroll
    for (int kk = 0; kk < 2; ++kk) {
      bf16x8 af[4], bg[4];
#pragma unroll
      for (int f = 0; f < 4; ++f) {
        const int bA = (((wr * 64 + f * 16 + cl) * 128) + kk * 64 + rg * 16) ^ ((cl & 7) << 4);
        const int bB = (((wc * 64 + f * 16 + cl) * 128) + kk * 64 + rg * 16) ^ ((cl & 7) << 4);
        af[f] = *reinterpret_cast<const bf16x8*>(reinterpret_cast<const char*>(As) + bA);
        bg[f] = *reinterpret_cast<const bf16x8*>(reinterpret_cast<const char*>(Bs) + bB);
      }
#pragma unroll
      for (int i = 0; i < 4; ++i)
#pragma unroll
        for (int j = 0; j < 4; ++j)
          acc[i][j] = __builtin_amdgcn_mfma_f32_16x16x32_bf16(af[i], bg[j], acc[i][j], 0, 0, 0);
    }
    __syncthreads();
  }

  // epilogue: d2 = a2 + b2 - 2*dot ; per-row min over this block's 128 cols
  float bc[4];
#pragma unroll
  for (int fn = 0; fn < 4; ++fn) bc[fn] = b2[m0 + wc * 64 + fn * 16 + cl];

  u64* sh = reinterpret_cast<u64*>(As);  // 128 rows x 2 wc slots = 2KB

#pragma unroll
  for (int fm = 0; fm < 4; ++fm) {
#pragma unroll
    for (int j = 0; j < 4; ++j) {
      const int rowL = wr * 64 + fm * 16 + rg * 4 + j;  // C/D: col=lane&15, row=(lane>>4)*4+reg
      const float ar = a2[n0 + rowL];
      float best = INFF;
      int bidx = 0x7FFFFFFF;
#pragma unroll
      for (int fn = 0; fn < 4; ++fn) {
        const float d2 = ar + bc[fn] - 2.0f * acc[fm][fn][j];
        const int col = m0 + wc * 64 + fn * 16 + cl;
        if (d2 < best || (d2 == best && col < bidx)) { best = d2; bidx = col; }
      }
#pragma unroll
      for (int msk = 1; msk < 16; msk <<= 1) {
        const float ov = __shfl_xor(best, msk);
        const int oi = __shfl_xor(bidx, msk);
        if (ov < best || (ov == best && oi < bidx)) { best = ov; bidx = oi; }
      }
      if (cl == 0) sh[rowL * 2 + wc] = ((u64)__float_as_uint(fmaxf(best, 0.0f)) << 32) | (unsigned)bidx;
    }
  }
  __syncthreads();
  if (wc == 0) {
    const int row = wr * 64 + lane;
    const u64 v0 = sh[row * 2], v1 = sh[row * 2 + 1];
    atomicMin(&packed[n0 + row], v0 < v1 ? v0 : v1);
  }
}

// ---------------- candidate rows near the max ----------------
__global__ __launch_bounds__(256) void cand_kernel(const u64* __restrict__ packed,
                                                   int* __restrict__ cand) {
  const int tid = threadIdx.x;
  float mx = -1.f;
  for (int n = tid; n < NP; n += 256) {
    const float v = __uint_as_float((unsigned)(packed[n] >> 32));
    mx = fmaxf(mx, v);
  }
#pragma unroll
  for (int m = 1; m < 64; m <<= 1) mx = fmaxf(mx, __shfl_xor(mx, m));
  __shared__ float wmax[4];
  __shared__ float smax;
  if ((tid & 63) == 0) wmax[tid >> 6] = mx;
  __syncthreads();
  if (tid == 0) {
    smax = fmaxf(fmaxf(wmax[0], wmax[1]), fmaxf(wmax[2], wmax[3]));
    cand[0] = 0;
  }
  __syncthreads();
  const float thr = smax - 4.0f;  // d^2 margin; bf16 error sigma ~0.22
  for (int n = tid; n < NP; n += 256) {
    const float v = __uint_as_float((unsigned)(packed[n] >> 32));
    if (v >= thr) {
      const int slot = atomicAdd(&cand[0], 1);
      if (slot < 256) cand[1 + slot] = n;
    }
  }
}

// ---------------- exact fp32 refinement of candidate rows ----------------
__global__ __launch_bounds__(256) void refine_kernel(const float* __restrict__ patch,
                                                     const float* __restrict__ lib,
                                                     const int* __restrict__ cand,
                                                     u64* __restrict__ refined) {
  const int c = blockIdx.x;
  const int cnt = min(cand[0], 256);
  if (c >= cnt) return;
  const int chunk = blockIdx.y;  // 64 chunks x 1024 rows
  const int r = cand[1 + c];
  __shared__ float a[DIM];
  const int tid = threadIdx.x, lane = tid & 63, w = tid >> 6;
  for (int i = tid; i < DIM; i += 256) a[i] = patch[(size_t)r * DIM + i];
  __syncthreads();
  for (int it = 0; it < 256; ++it) {
    const int m = chunk * 1024 + w * 256 + it;
    const float* br = lib + (size_t)m * DIM;
    float s = 0.f;
#pragma unroll
    for (int k = 0; k < 6; ++k) {
      const float d = a[lane + k * 64] - br[lane + k * 64];
      s += d * d;
    }
#pragma unroll
    for (int msk = 1; msk < 64; msk <<= 1) s += __shfl_xor(s, msk);
    if (lane == 0) {
      const u64 p = ((u64)__float_as_uint(s) << 32) | (unsigned)m;
      atomicMin(&refined[c], p);
    }
  }
}

// ---------------- pick exact argmax row ----------------
__global__ __launch_bounds__(256) void pick_kernel(const u64* __restrict__ refined,
                                                   const int* __restrict__ cand,
                                                   int* __restrict__ scal_i,
                                                   float* __restrict__ scal_f) {
  const int tid = threadIdx.x, lane = tid & 63, w = tid >> 6;
  const int cnt = min(cand[0], 256);
  float v = -1.f;
  int nrow = 0x7FFFFFFF;
  int mi = 0;
  if (tid < cnt) {
    const u64 p = refined[tid];
    v = __uint_as_float((unsigned)(p >> 32));
    nrow = cand[1 + tid];
    mi = (int)(unsigned)p;
  }
#pragma unroll
  for (int msk = 1; msk < 64; msk <<= 1) {
    const float ov = __shfl_xor(v, msk);
    const int on = __shfl_xor(nrow, msk);
    const int om = __shfl_xor(mi, msk);
    if (ov > v || (ov == v && on < nrow)) { v = ov; nrow = on; mi = om; }
  }
  __shared__ float sv[4]; __shared__ int sn[4]; __shared__ int sm[4];
  if (lane == 0) { sv[w] = v; sn[w] = nrow; sm[w] = mi; }
  __syncthreads();
  if (tid == 0) {
    for (int k = 1; k < 4; ++k)
      if (sv[k] > v || (sv[k] == v && sn[k] < nrow)) { v = sv[k]; nrow = sn[k]; mi = sm[k]; }
    scal_i[0] = nrow;       // s_idx
    scal_i[1] = mi;         // m_star index
    scal_f[0] = sqrtf(fmaxf(v, 0.f));  // s_star
  }
}

// ---------------- fused w_dist + per-wave top-3 (stage 1) ----------------
__device__ __forceinline__ bool lt2(float v, int i, float v2, int i2) {
  return v < v2 || (v == v2 && i < i2);
}
__device__ __forceinline__ void ins3(float v, int i, float* tv, int* ti) {
  if (lt2(v, i, tv[2], ti[2])) {
    tv[2] = v; ti[2] = i;
    if (lt2(tv[2], ti[2], tv[1], ti[1])) {
      float a = tv[1]; int b = ti[1]; tv[1] = tv[2]; ti[1] = ti[2]; tv[2] = a; ti[2] = b;
    }
    if (lt2(tv[1], ti[1], tv[0], ti[0])) {
      float a = tv[0]; int b = ti[0]; tv[0] = tv[1]; ti[0] = ti[1]; tv[1] = a; ti[1] = b;
    }
  }
}

__global__ __launch_bounds__(256) void wtop_kernel(const float* __restrict__ lib,
                                                   const int* __restrict__ scal_i,
                                                   u64* __restrict__ t3) {
  __shared__ float a[DIM];
  const int tid = threadIdx.x, lane = tid & 63, w = tid >> 6;
  const int ms = scal_i[1];
  for (int i = tid; i < DIM; i += 256) a[i] = lib[(size_t)ms * DIM + i];
  __syncthreads();
  const int gw = blockIdx.x * 4 + w;  // 0..1023, 64 rows each
  float tv[3] = {INFF, INFF, INFF};
  int ti[3] = {0x7FFFFFFF, 0x7FFFFFFF, 0x7FFFFFFF};
  for (int it = 0; it < 64; ++it) {
    const int m = gw * 64 + it;
    const float* br = lib + (size_t)m * DIM;
    float s = 0.f;
#pragma unroll
    for (int k = 0; k < 6; ++k) {
      const float d = a[lane + k * 64] - br[lane + k * 64];
      s += d * d;
    }
#pragma unroll
    for (int msk = 1; msk < 64; msk <<= 1) s += __shfl_xor(s, msk);
    ins3(s, m, tv, ti);  // all lanes hold identical s -> identical top3
  }
  if (lane == 0) {
#pragma unroll
    for (int k = 0; k < 3; ++k)
      t3[gw * 3 + k] = ((u64)__float_as_uint(tv[k]) << 32) | (unsigned)ti[k];
  }
}

// ---------------- stage-2 top-3 + final score ----------------
__device__ __forceinline__ void ins3u(u64 x, u64* v) {
  if (x < v[2]) {
    v[2] = x;
    if (v[2] < v[1]) { u64 t = v[1]; v[1] = v[2]; v[2] = t; }
    if (v[1] < v[0]) { u64 t = v[0]; v[0] = v[1]; v[1] = t; }
  }
}

__global__ __launch_bounds__(256) void final_kernel(const u64* __restrict__ t3,
                                                    const float* __restrict__ patch,
                                                    const float* __restrict__ lib,
                                                    const int* __restrict__ scal_i,
                                                    const float* __restrict__ scal_f,
                                                    float* __restrict__ out) {
  const int tid = threadIdx.x, lane = tid & 63, w = tid >> 6;
  u64 v[3] = {~0ull, ~0ull, ~0ull};
  for (int i = tid; i < 3072; i += 256) ins3u(t3[i], v);
#pragma unroll
  for (int msk = 1; msk < 64; msk <<= 1) {
    u64 o0 = __shfl_xor(v[0], msk);
    u64 o1 = __shfl_xor(v[1], msk);
    u64 o2 = __shfl_xor(v[2], msk);
    ins3u(o0, v); ins3u(o1, v); ins3u(o2, v);
  }
  __shared__ u64 sv[12];
  __shared__ int nn[2]; __shared__ float kk[2];
  if (lane == 0) {
#pragma unroll
    for (int k = 0; k < 3; ++k) sv[w * 3 + k] = v[k];
  }
  __syncthreads();
  if (tid == 0) {
    u64 fv[3] = {~0ull, ~0ull, ~0ull};
    for (int k = 0; k < 12; ++k) ins3u(sv[k], fv);
    nn[0] = (int)(unsigned)fv[1];  // skip fv[0] == m_star itself
    nn[1] = (int)(unsigned)fv[2];
  }
  __syncthreads();
  if (w < 2) {
    const int s_idx = scal_i[0];
    const int nnx = nn[w];
    float s = 0.f;
#pragma unroll
    for (int k = 0; k < 6; ++k) {
      const float d = patch[(size_t)s_idx * DIM + lane + k * 64] - lib[(size_t)nnx * DIM + lane + k * 64];
      s += d * d;
    }
#pragma unroll
    for (int msk = 1; msk < 64; msk <<= 1) s += __shfl_xor(s, msk);
    if (lane == 0) kk[w] = sqrtf(s);
  }
  __syncthreads();
  if (tid == 0) {
    const float s_star = scal_f[0];
    const float Ds = 19.59591794f;  // sqrt(384)
    const float wt = 1.0f - expf(s_star / Ds) / (expf(kk[0] / Ds) + expf(kk[1] / Ds));
    out[0] = wt * s_star;
  }
}

// ---------------- score map: resize (reads packed directly) + blur ----------------
__device__ __forceinline__ float mval(const u64* packed, int n) {
  return sqrtf(fmaxf(__uint_as_float((unsigned)(packed[n] >> 32)), 0.f));
}

__global__ __launch_bounds__(256) void resize_kernel(const u64* __restrict__ packed,
                                                     float* __restrict__ t1) {
  const int idx = blockIdx.x * 256 + threadIdx.x;  // 262144
  const int x = idx & 511, y = idx >> 9;
  const float sy = y * 0.125f - 0.4375f;
  const float sx = x * 0.125f - 0.4375f;
  const int y0 = (int)floorf(sy); const float fy = sy - (float)y0;
  const int x0 = (int)floorf(sx); const float fx = sx - (float)x0;
  const int ya = max(y0, 0), yb = min(y0 + 1, 63);
  const int xa = max(x0, 0), xb = min(x0 + 1, 63);
  const float v00 = mval(packed, ya * 64 + xa), v01 = mval(packed, ya * 64 + xb);
  const float v10 = mval(packed, yb * 64 + xa), v11 = mval(packed, yb * 64 + xb);
  t1[idx] = (1.f - fy) * ((1.f - fx) * v00 + fx * v01) + fy * ((1.f - fx) * v10 + fx * v11);
}

__device__ __constant__ float BW[9] = {
    0.0816741424f, 0.1016453893f, 0.1188358540f, 0.1305155396f, 0.1346581512f,
    0.1305155396f, 0.1188358540f, 0.1016453893f, 0.0816741424f};

__global__ __launch_bounds__(256) void blurv_kernel(const float* __restrict__ t1,
                                                    float* __restrict__ t2) {
  const int idx = blockIdx.x * 256 + threadIdx.x;
  const int x = idx & 511, y = idx >> 9;
  float s = 0.f;
#pragma unroll
  for (int k = -4; k <= 4; ++k) {
    const int yy = y + k;
    if (yy >= 0 && yy < 512) s += BW[k + 4] * t1[yy * 512 + x];
  }
  t2[idx] = s;
}

__global__ __launch_bounds__(256) void blurh_kernel(const float* __restrict__ t2,
                                                    float* __restrict__ out) {
  const int idx = blockIdx.x * 256 + threadIdx.x;
  const int x = idx & 511, y = idx >> 9;
  float s = 0.f;
#pragma unroll
  for (int k = -4; k <= 4; ++k) {
    const int xx = x + k;
    if (xx >= 0 && xx < 512) s += BW[k + 4] * t2[y * 512 + xx];
  }
  out[idx] = s;
}

extern "C" void kernel_launch(void* const* d_in, const int* in_sizes, int n_in,
                              void* d_out, int out_size, void* d_ws, size_t ws_size,
                              hipStream_t stream) {
  const float* patch = (const float*)d_in[0];
  const float* lib = (const float*)d_in[1];
  float* out = (float*)d_out;

  char* ws = (char*)d_ws;
  size_t off = 0;
  auto alloc = [&](size_t bytes) {
    void* p = ws + off;
    off += (bytes + 255) & ~(size_t)255;
    return p;
  };
  u16* Abf = (u16*)alloc((size_t)NP * DIM * 2);
  u16* Bbf = (u16*)alloc((size_t)ML * DIM * 2);
  float* a2 = (float*)alloc(NP * 4);
  float* b2 = (float*)alloc(ML * 4);
  u64* packed = (u64*)alloc(NP * 8);
  u64* refined = (u64*)alloc(256 * 8);
  int* cand = (int*)alloc(257 * 4);
  int* scal_i = (int*)alloc(64);
  float* scal_f = (float*)alloc(64);
  u64* t3 = (u64*)alloc(1024 * 3 * 8);
  float* t1 = (float*)alloc(512 * 512 * 4);
  float* t2 = (float*)alloc(512 * 512 * 4);

  hipMemsetAsync(packed, 0xFF, NP * 8, stream);
  hipMemsetAsync(refined, 0xFF, 256 * 8, stream);

  prep_kernel<<<NP, 128, 0, stream>>>(patch, Abf, a2);
  prep_kernel<<<ML, 128, 0, stream>>>(lib, Bbf, b2);
  gemm_min_kernel<<<16384, 256, 0, stream>>>(Abf, Bbf, a2, b2, packed);
  cand_kernel<<<1, 256, 0, stream>>>(packed, cand);
  refine_kernel<<<dim3(256, 64), 256, 0, stream>>>(patch, lib, cand, refined);
  pick_kernel<<<1, 256, 0, stream>>>(refined, cand, scal_i, scal_f);
  wtop_kernel<<<256, 256, 0, stream>>>(lib, scal_i, t3);
  final_kernel<<<1, 256, 0, stream>>>(t3, patch, lib, scal_i, scal_f, out);
  resize_kernel<<<1024, 256, 0, stream>>>(packed, t1);
  blurv_kernel<<<1024, 256, 0, stream>>>(t1, t2);
  blurh_kernel<<<1024, 256, 0, stream>>>(t2, out + 1);
}

// Round 3
// 692.579 us; speedup vs baseline: 2.6263x; 2.0763x over previous
//
#include <hip/hip_runtime.h>

#define NP 4096
#define DIM 384
#define ML 65536
#define INFF 3.402823466e38f

typedef short bf16x8 __attribute__((ext_vector_type(8)));
typedef float f32x4 __attribute__((ext_vector_type(4)));
typedef unsigned short u16;
typedef unsigned long long u64;

typedef __attribute__((address_space(1))) unsigned int as1_u32;
typedef __attribute__((address_space(3))) unsigned int as3_u32;

__device__ __forceinline__ void gl_lds16(const void* g, void* l) {
  __builtin_amdgcn_global_load_lds((const as1_u32*)g, (as3_u32*)l, 16, 0, 0);
}

__device__ __forceinline__ u16 f2bf(float x) {
  unsigned u = __float_as_uint(x);
  u += 0x7FFFu + ((u >> 16) & 1u);
  return (u16)(u >> 16);
}

// ---------------- prep: fp32 -> bf16 + row sumsq (wave per row) ----------------
__global__ __launch_bounds__(256) void prep_kernel(const float* __restrict__ src,
                                                   u16* __restrict__ dst,
                                                   float* __restrict__ norms) {
  const int row = blockIdx.x * 4 + (threadIdx.x >> 6);
  const int lane = threadIdx.x & 63;
  float s = 0.f;
#pragma unroll
  for (int j = 0; j < 3; ++j) {
    const float2 v = *reinterpret_cast<const float2*>(src + (size_t)row * DIM + j * 128 + lane * 2);
    s += v.x * v.x + v.y * v.y;
    const unsigned p = ((unsigned)f2bf(v.y) << 16) | (unsigned)f2bf(v.x);
    *reinterpret_cast<unsigned*>(dst + (size_t)row * DIM + j * 128 + lane * 2) = p;
  }
#pragma unroll
  for (int m = 1; m < 64; m <<= 1) s += __shfl_xor(s, m);
  if (lane == 0) norms[row] = s;
}

// ---------------- fused bf16 GEMM + row-min (T2 swizzle + T1 XCD remap) ----------------
__global__ __launch_bounds__(256) void gemm_min_kernel(const u16* __restrict__ Abf,
                                                       const u16* __restrict__ Bbf,
                                                       const float* __restrict__ a2,
                                                       const float* __restrict__ b2,
                                                       u64* __restrict__ packed) {
  __shared__ __align__(16) u16 As[128 * 64];
  __shared__ __align__(16) u16 Bs[128 * 64];
  const int tid = threadIdx.x;
  const int lane = tid & 63;
  const int w = tid >> 6;
  const int wr = w >> 1, wc = w & 1;

  const int orig = blockIdx.x;
  const int logical = (orig & 7) * 2048 + (orig >> 3);
  const int xt = logical & 31;
  const int yt = logical >> 5;
  const int n0 = xt * 128;   // patch rows
  const int m0 = yt * 128;   // lib rows (output cols)
  const int cl = lane & 15, rg = lane >> 4;

  f32x4 acc[4][4] = {};

  for (int kt = 0; kt < 6; ++kt) {
    const int k0 = kt * 64;
#pragma unroll
    for (int i = 0; i < 4; ++i) {
      const int P = i * 4096 + tid * 16;     // linear LDS dest byte
      const int r = P >> 7;                  // tile row (128B per row)
      const int L = P ^ ((r & 7) << 4);      // inverse-swizzled source offset
      const int c = (L & 127) >> 1;          // ushort col within row
      gl_lds16(Abf + (size_t)(n0 + r) * DIM + k0 + c, (char*)As + P);
      gl_lds16(Bbf + (size_t)(m0 + r) * DIM + k0 + c, (char*)Bs + P);
    }
    __syncthreads();
#pragma unroll
    for (int kk = 0; kk < 2; ++kk) {
      bf16x8 af[4], bg[4];
#pragma unroll
      for (int f = 0; f < 4; ++f) {
        const int bA = (((wr * 64 + f * 16 + cl) * 128) + kk * 64 + rg * 16) ^ ((cl & 7) << 4);
        const int bB = (((wc * 64 + f * 16 + cl) * 128) + kk * 64 + rg * 16) ^ ((cl & 7) << 4);
        af[f] = *reinterpret_cast<const bf16x8*>(reinterpret_cast<const char*>(As) + bA);
        bg[f] = *reinterpret_cast<const bf16x8*>(reinterpret_cast<const char*>(Bs) + bB);
      }
#pragma unroll
      for (int i = 0; i < 4; ++i)
#pragma unroll
        for (int j = 0; j < 4; ++j)
          acc[i][j] = __builtin_amdgcn_mfma_f32_16x16x32_bf16(af[i], bg[j], acc[i][j], 0, 0, 0);
    }
    __syncthreads();
  }

  float bc[4];
#pragma unroll
  for (int fn = 0; fn < 4; ++fn) bc[fn] = b2[m0 + wc * 64 + fn * 16 + cl];

  u64* sh = reinterpret_cast<u64*>(As);  // 128 rows x 2 wc slots = 2KB

#pragma unroll
  for (int fm = 0; fm < 4; ++fm) {
#pragma unroll
    for (int j = 0; j < 4; ++j) {
      const int rowL = wr * 64 + fm * 16 + rg * 4 + j;  // C/D: col=lane&15, row=(lane>>4)*4+reg
      const float ar = a2[n0 + rowL];
      float best = INFF;
      int bidx = 0x7FFFFFFF;
#pragma unroll
      for (int fn = 0; fn < 4; ++fn) {
        const float d2 = ar + bc[fn] - 2.0f * acc[fm][fn][j];
        const int col = m0 + wc * 64 + fn * 16 + cl;
        if (d2 < best || (d2 == best && col < bidx)) { best = d2; bidx = col; }
      }
#pragma unroll
      for (int msk = 1; msk < 16; msk <<= 1) {
        const float ov = __shfl_xor(best, msk);
        const int oi = __shfl_xor(bidx, msk);
        if (ov < best || (ov == best && oi < bidx)) { best = ov; bidx = oi; }
      }
      if (cl == 0) sh[rowL * 2 + wc] = ((u64)__float_as_uint(fmaxf(best, 0.0f)) << 32) | (unsigned)bidx;
    }
  }
  __syncthreads();
  if (wc == 0) {
    const int row = wr * 64 + lane;
    const u64 v0 = sh[row * 2], v1 = sh[row * 2 + 1];
    atomicMin(&packed[n0 + row], v0 < v1 ? v0 : v1);
  }
}

// ---------------- candidate rows near the max ----------------
__global__ __launch_bounds__(256) void cand_kernel(const u64* __restrict__ packed,
                                                   int* __restrict__ cand) {
  const int tid = threadIdx.x;
  float mx = -1.f;
  for (int n = tid; n < NP; n += 256) {
    const float v = __uint_as_float((unsigned)(packed[n] >> 32));
    mx = fmaxf(mx, v);
  }
#pragma unroll
  for (int m = 1; m < 64; m <<= 1) mx = fmaxf(mx, __shfl_xor(mx, m));
  __shared__ float wmax[4];
  __shared__ float smax;
  if ((tid & 63) == 0) wmax[tid >> 6] = mx;
  __syncthreads();
  if (tid == 0) {
    smax = fmaxf(fmaxf(wmax[0], wmax[1]), fmaxf(wmax[2], wmax[3]));
    cand[0] = 0;
  }
  __syncthreads();
  const float thr = smax - 4.0f;  // d^2 margin >> bf16 error
  for (int n = tid; n < NP; n += 256) {
    const float v = __uint_as_float((unsigned)(packed[n] >> 32));
    if (v >= thr) {
      const int slot = atomicAdd(&cand[0], 1);
      if (slot < 256) cand[1 + slot] = n;
    }
  }
}

// ---------------- exact fp32 refinement: block owns 32 lib rows ----------------
__global__ __launch_bounds__(256) void refine_kernel(const float* __restrict__ patch,
                                                     const float* __restrict__ lib,
                                                     const int* __restrict__ cand,
                                                     u64* __restrict__ refined) {
  const int cnt = min(cand[0], 256);
  const int tid = threadIdx.x, lane = tid & 63, w = tid >> 6;
  const int base = blockIdx.x * 32;  // 2048 blocks
  __shared__ float a[8][DIM];        // 12 KB candidate staging
  __shared__ u64 rb[8][4];

  for (int g0 = 0; g0 < cnt; g0 += 8) {
    const int gc = min(cnt - g0, 8);
    for (int i = tid; i < gc * DIM; i += 256) {
      const int c = i / DIM, e = i - c * DIM;
      a[c][e] = patch[(size_t)cand[1 + g0 + c] * DIM + e];
    }
    __syncthreads();

    u64 wbest[8];
#pragma unroll
    for (int c = 0; c < 8; ++c) wbest[c] = ~0ull;

    for (int it = 0; it < 8; ++it) {
      const int m = base + w * 8 + it;
      float lr[6];
#pragma unroll
      for (int j = 0; j < 3; ++j) {
        const float2 v = *reinterpret_cast<const float2*>(lib + (size_t)m * DIM + j * 128 + lane * 2);
        lr[j * 2] = v.x; lr[j * 2 + 1] = v.y;
      }
#pragma unroll
      for (int c = 0; c < 8; ++c) {
        if (c >= gc) break;
        float s = 0.f;
#pragma unroll
        for (int j = 0; j < 3; ++j) {
          const float d0 = lr[j * 2] - a[c][j * 128 + lane * 2];
          const float d1 = lr[j * 2 + 1] - a[c][j * 128 + lane * 2 + 1];
          s += d0 * d0 + d1 * d1;
        }
#pragma unroll
        for (int msk = 1; msk < 64; msk <<= 1) s += __shfl_xor(s, msk);
        const u64 p = ((u64)__float_as_uint(s) << 32) | (unsigned)m;
        wbest[c] = p < wbest[c] ? p : wbest[c];
      }
    }
    if (lane == 0) {
#pragma unroll
      for (int c = 0; c < 8; ++c)
        if (c < gc) rb[c][w] = wbest[c];
    }
    __syncthreads();
    if (tid < gc) {
      u64 b = rb[tid][0];
#pragma unroll
      for (int k = 1; k < 4; ++k) b = rb[tid][k] < b ? rb[tid][k] : b;
      atomicMin(&refined[g0 + tid], b);
    }
    __syncthreads();
  }
}

// ---------------- pick exact argmax row ----------------
__global__ __launch_bounds__(256) void pick_kernel(const u64* __restrict__ refined,
                                                   const int* __restrict__ cand,
                                                   int* __restrict__ scal_i,
                                                   float* __restrict__ scal_f) {
  const int tid = threadIdx.x, lane = tid & 63, w = tid >> 6;
  const int cnt = min(cand[0], 256);
  float v = -1.f;
  int nrow = 0x7FFFFFFF;
  int mi = 0;
  if (tid < cnt) {
    const u64 p = refined[tid];
    v = __uint_as_float((unsigned)(p >> 32));
    nrow = cand[1 + tid];
    mi = (int)(unsigned)p;
  }
#pragma unroll
  for (int msk = 1; msk < 64; msk <<= 1) {
    const float ov = __shfl_xor(v, msk);
    const int on = __shfl_xor(nrow, msk);
    const int om = __shfl_xor(mi, msk);
    if (ov > v || (ov == v && on < nrow)) { v = ov; nrow = on; mi = om; }
  }
  __shared__ float sv[4]; __shared__ int sn[4]; __shared__ int sm[4];
  if (lane == 0) { sv[w] = v; sn[w] = nrow; sm[w] = mi; }
  __syncthreads();
  if (tid == 0) {
    for (int k = 1; k < 4; ++k)
      if (sv[k] > v || (sv[k] == v && sn[k] < nrow)) { v = sv[k]; nrow = sn[k]; mi = sm[k]; }
    scal_i[0] = nrow;       // s_idx
    scal_i[1] = mi;         // m_star index
    scal_f[0] = sqrtf(fmaxf(v, 0.f));  // s_star
  }
}

// ---------------- fused w_dist + per-block top-3 (block owns 32 rows) ----------------
__device__ __forceinline__ void ins3u(u64 x, u64* v) {
  if (x < v[2]) {
    v[2] = x;
    if (v[2] < v[1]) { u64 t = v[1]; v[1] = v[2]; v[2] = t; }
    if (v[1] < v[0]) { u64 t = v[0]; v[0] = v[1]; v[1] = t; }
  }
}

__global__ __launch_bounds__(256) void wtop_kernel(const float* __restrict__ lib,
                                                   const int* __restrict__ scal_i,
                                                   u64* __restrict__ t3) {
  __shared__ float a[DIM];
  __shared__ u64 sv[12];
  const int tid = threadIdx.x, lane = tid & 63, w = tid >> 6;
  const int ms = scal_i[1];
  for (int i = tid; i < DIM; i += 256) a[i] = lib[(size_t)ms * DIM + i];
  __syncthreads();
  const int base = blockIdx.x * 32;  // 2048 blocks
  u64 v[3] = {~0ull, ~0ull, ~0ull};
  for (int it = 0; it < 8; ++it) {
    const int m = base + w * 8 + it;
    float s = 0.f;
#pragma unroll
    for (int j = 0; j < 3; ++j) {
      const float2 lv = *reinterpret_cast<const float2*>(lib + (size_t)m * DIM + j * 128 + lane * 2);
      const float d0 = lv.x - a[j * 128 + lane * 2];
      const float d1 = lv.y - a[j * 128 + lane * 2 + 1];
      s += d0 * d0 + d1 * d1;
    }
#pragma unroll
    for (int msk = 1; msk < 64; msk <<= 1) s += __shfl_xor(s, msk);
    ins3u(((u64)__float_as_uint(s) << 32) | (unsigned)m, v);  // wave-uniform
  }
  if (lane == 0) {
#pragma unroll
    for (int k = 0; k < 3; ++k) sv[w * 3 + k] = v[k];
  }
  __syncthreads();
  if (tid == 0) {
    u64 fv[3] = {~0ull, ~0ull, ~0ull};
    for (int k = 0; k < 12; ++k) ins3u(sv[k], fv);
#pragma unroll
    for (int k = 0; k < 3; ++k) t3[blockIdx.x * 3 + k] = fv[k];
  }
}

// ---------------- stage-2 top-3 + final score ----------------
__global__ __launch_bounds__(256) void final_kernel(const u64* __restrict__ t3,
                                                    const float* __restrict__ patch,
                                                    const float* __restrict__ lib,
                                                    const int* __restrict__ scal_i,
                                                    const float* __restrict__ scal_f,
                                                    float* __restrict__ out) {
  const int tid = threadIdx.x, lane = tid & 63, w = tid >> 6;
  u64 v[3] = {~0ull, ~0ull, ~0ull};
  for (int i = tid; i < 6144; i += 256) ins3u(t3[i], v);
#pragma unroll
  for (int msk = 1; msk < 64; msk <<= 1) {
    u64 o0 = __shfl_xor(v[0], msk);
    u64 o1 = __shfl_xor(v[1], msk);
    u64 o2 = __shfl_xor(v[2], msk);
    ins3u(o0, v); ins3u(o1, v); ins3u(o2, v);
  }
  __shared__ u64 sv[12];
  __shared__ int nn[2]; __shared__ float kk[2];
  if (lane == 0) {
#pragma unroll
    for (int k = 0; k < 3; ++k) sv[w * 3 + k] = v[k];
  }
  __syncthreads();
  if (tid == 0) {
    u64 fv[3] = {~0ull, ~0ull, ~0ull};
    for (int k = 0; k < 12; ++k) ins3u(sv[k], fv);
    nn[0] = (int)(unsigned)fv[1];  // skip fv[0] == m_star itself
    nn[1] = (int)(unsigned)fv[2];
  }
  __syncthreads();
  if (w < 2) {
    const int s_idx = scal_i[0];
    const int nnx = nn[w];
    float s = 0.f;
#pragma unroll
    for (int k = 0; k < 6; ++k) {
      const float d = patch[(size_t)s_idx * DIM + lane + k * 64] - lib[(size_t)nnx * DIM + lane + k * 64];
      s += d * d;
    }
#pragma unroll
    for (int msk = 1; msk < 64; msk <<= 1) s += __shfl_xor(s, msk);
    if (lane == 0) kk[w] = sqrtf(s);
  }
  __syncthreads();
  if (tid == 0) {
    const float s_star = scal_f[0];
    const float Ds = 19.59591794f;  // sqrt(384)
    const float wt = 1.0f - expf(s_star / Ds) / (expf(kk[0] / Ds) + expf(kk[1] / Ds));
    out[0] = wt * s_star;
  }
}

// ---------------- score map: resize (reads packed directly) + blur ----------------
__device__ __forceinline__ float mval(const u64* packed, int n) {
  return sqrtf(fmaxf(__uint_as_float((unsigned)(packed[n] >> 32)), 0.f));
}

__global__ __launch_bounds__(256) void resize_kernel(const u64* __restrict__ packed,
                                                     float* __restrict__ t1) {
  const int idx = blockIdx.x * 256 + threadIdx.x;  // 262144
  const int x = idx & 511, y = idx >> 9;
  const float sy = y * 0.125f - 0.4375f;
  const float sx = x * 0.125f - 0.4375f;
  const int y0 = (int)floorf(sy); const float fy = sy - (float)y0;
  const int x0 = (int)floorf(sx); const float fx = sx - (float)x0;
  const int ya = max(y0, 0), yb = min(y0 + 1, 63);
  const int xa = max(x0, 0), xb = min(x0 + 1, 63);
  const float v00 = mval(packed, ya * 64 + xa), v01 = mval(packed, ya * 64 + xb);
  const float v10 = mval(packed, yb * 64 + xa), v11 = mval(packed, yb * 64 + xb);
  t1[idx] = (1.f - fy) * ((1.f - fx) * v00 + fx * v01) + fy * ((1.f - fx) * v10 + fx * v11);
}

__device__ __constant__ float BW[9] = {
    0.0816741424f, 0.1016453893f, 0.1188358540f, 0.1305155396f, 0.1346581512f,
    0.1305155396f, 0.1188358540f, 0.1016453893f, 0.0816741424f};

__global__ __launch_bounds__(256) void blurv_kernel(const float* __restrict__ t1,
                                                    float* __restrict__ t2) {
  const int idx = blockIdx.x * 256 + threadIdx.x;
  const int x = idx & 511, y = idx >> 9;
  float s = 0.f;
#pragma unroll
  for (int k = -4; k <= 4; ++k) {
    const int yy = y + k;
    if (yy >= 0 && yy < 512) s += BW[k + 4] * t1[yy * 512 + x];
  }
  t2[idx] = s;
}

__global__ __launch_bounds__(256) void blurh_kernel(const float* __restrict__ t2,
                                                    float* __restrict__ out) {
  const int idx = blockIdx.x * 256 + threadIdx.x;
  const int x = idx & 511, y = idx >> 9;
  float s = 0.f;
#pragma unroll
  for (int k = -4; k <= 4; ++k) {
    const int xx = x + k;
    if (xx >= 0 && xx < 512) s += BW[k + 4] * t2[y * 512 + xx];
  }
  out[idx] = s;
}

extern "C" void kernel_launch(void* const* d_in, const int* in_sizes, int n_in,
                              void* d_out, int out_size, void* d_ws, size_t ws_size,
                              hipStream_t stream) {
  const float* patch = (const float*)d_in[0];
  const float* lib = (const float*)d_in[1];
  float* out = (float*)d_out;

  char* ws = (char*)d_ws;
  size_t off = 0;
  auto alloc = [&](size_t bytes) {
    void* p = ws + off;
    off += (bytes + 255) & ~(size_t)255;
    return p;
  };
  u16* Abf = (u16*)alloc((size_t)NP * DIM * 2);
  u16* Bbf = (u16*)alloc((size_t)ML * DIM * 2);
  float* a2 = (float*)alloc(NP * 4);
  float* b2 = (float*)alloc(ML * 4);
  u64* packed = (u64*)alloc(NP * 8);
  u64* refined = (u64*)alloc(256 * 8);
  int* cand = (int*)alloc(257 * 4);
  int* scal_i = (int*)alloc(64);
  float* scal_f = (float*)alloc(64);
  u64* t3 = (u64*)alloc(2048 * 3 * 8);
  float* t1 = (float*)alloc(512 * 512 * 4);
  float* t2 = (float*)alloc(512 * 512 * 4);

  hipMemsetAsync(packed, 0xFF, NP * 8, stream);
  hipMemsetAsync(refined, 0xFF, 256 * 8, stream);

  prep_kernel<<<NP / 4, 256, 0, stream>>>(patch, Abf, a2);
  prep_kernel<<<ML / 4, 256, 0, stream>>>(lib, Bbf, b2);
  gemm_min_kernel<<<16384, 256, 0, stream>>>(Abf, Bbf, a2, b2, packed);
  cand_kernel<<<1, 256, 0, stream>>>(packed, cand);
  refine_kernel<<<2048, 256, 0, stream>>>(patch, lib, cand, refined);
  pick_kernel<<<1, 256, 0, stream>>>(refined, cand, scal_i, scal_f);
  wtop_kernel<<<2048, 256, 0, stream>>>(lib, scal_i, t3);
  final_kernel<<<1, 256, 0, stream>>>(t3, patch, lib, scal_i, scal_f, out);
  resize_kernel<<<1024, 256, 0, stream>>>(packed, t1);
  blurv_kernel<<<1024, 256, 0, stream>>>(t1, t2);
  blurh_kernel<<<1024, 256, 0, stream>>>(t2, out + 1);
}

// Round 4
// 626.023 us; speedup vs baseline: 2.9056x; 1.1063x over previous
//
#include <hip/hip_runtime.h>

#define NP 4096
#define DIM 384
#define ML 65536
#define INFF 3.402823466e38f

typedef short bf16x8 __attribute__((ext_vector_type(8)));
typedef float f32x4 __attribute__((ext_vector_type(4)));
typedef unsigned short u16;
typedef unsigned long long u64;

typedef __attribute__((address_space(1))) unsigned int as1_u32;
typedef __attribute__((address_space(3))) unsigned int as3_u32;

__device__ __forceinline__ void gl_lds16(const void* g, void* l) {
  __builtin_amdgcn_global_load_lds((const as1_u32*)g, (as3_u32*)l, 16, 0, 0);
}

__device__ __forceinline__ u16 f2bf(float x) {
  unsigned u = __float_as_uint(x);
  u += 0x7FFFu + ((u >> 16) & 1u);
  return (u16)(u >> 16);
}

// ---------------- prep: fp32 -> bf16 + row sumsq (wave per row) ----------------
__global__ __launch_bounds__(256) void prep_kernel(const float* __restrict__ src,
                                                   u16* __restrict__ dst,
                                                   float* __restrict__ norms) {
  const int row = blockIdx.x * 4 + (threadIdx.x >> 6);
  const int lane = threadIdx.x & 63;
  float s = 0.f;
#pragma unroll
  for (int j = 0; j < 3; ++j) {
    const float2 v = *reinterpret_cast<const float2*>(src + (size_t)row * DIM + j * 128 + lane * 2);
    s += v.x * v.x + v.y * v.y;
    const unsigned p = ((unsigned)f2bf(v.y) << 16) | (unsigned)f2bf(v.x);
    *reinterpret_cast<unsigned*>(dst + (size_t)row * DIM + j * 128 + lane * 2) = p;
  }
#pragma unroll
  for (int m = 1; m < 64; m <<= 1) s += __shfl_xor(s, m);
  if (lane == 0) norms[row] = s;
}

// ---- fused bf16 GEMM + row-min (T2 swizzle + T1 remap + T3 2-phase dbuf) ----
__global__ __launch_bounds__(256) void gemm_min_kernel(const u16* __restrict__ Abf,
                                                       const u16* __restrict__ Bbf,
                                                       const float* __restrict__ a2,
                                                       const float* __restrict__ b2,
                                                       u64* __restrict__ packed) {
  __shared__ __align__(16) u16 As[2][8192];
  __shared__ __align__(16) u16 Bs[2][8192];
  const int tid = threadIdx.x;
  const int lane = tid & 63;
  const int w = tid >> 6;
  const int wr = w >> 1, wc = w & 1;

  const int orig = blockIdx.x;
  const int logical = (orig & 7) * 2048 + (orig >> 3);
  const int xt = logical & 31;
  const int yt = logical >> 5;
  const int n0 = xt * 128;   // patch rows
  const int m0 = yt * 128;   // lib rows (output cols)
  const int cl = lane & 15, rg = lane >> 4;

  // staging addresses (kt-invariant, advanced by +=64 per tile)
  const u16* ga[4]; const u16* gb[4]; int lof[4];
#pragma unroll
  for (int i = 0; i < 4; ++i) {
    const int P = i * 4096 + tid * 16;     // linear LDS dest byte
    const int r = P >> 7;                  // tile row (128B per row)
    const int L = P ^ ((r & 7) << 4);      // inverse-swizzled source offset
    const int c = (L & 127) >> 1;          // ushort col within row
    lof[i] = P;
    ga[i] = Abf + (size_t)(n0 + r) * DIM + c;
    gb[i] = Bbf + (size_t)(m0 + r) * DIM + c;
  }

  // fragment byte offsets (kt-invariant)
  int offA[2][4], offB[2][4];
#pragma unroll
  for (int kk = 0; kk < 2; ++kk)
#pragma unroll
    for (int f = 0; f < 4; ++f) {
      offA[kk][f] = (((wr * 64 + f * 16 + cl) * 128) + kk * 64 + rg * 16) ^ ((cl & 7) << 4);
      offB[kk][f] = (((wc * 64 + f * 16 + cl) * 128) + kk * 64 + rg * 16) ^ ((cl & 7) << 4);
    }

  // hoisted epilogue operand (overlaps with prologue staging)
  float bc[4];
#pragma unroll
  for (int fn = 0; fn < 4; ++fn) bc[fn] = b2[m0 + wc * 64 + fn * 16 + cl];

  f32x4 acc[4][4] = {};

  // prologue: stage tile 0 into buf 0
#pragma unroll
  for (int i = 0; i < 4; ++i) {
    gl_lds16(ga[i], (char*)As[0] + lof[i]);
    gl_lds16(gb[i], (char*)Bs[0] + lof[i]);
    ga[i] += 64; gb[i] += 64;
  }

#pragma unroll
  for (int kt = 0; kt < 6; ++kt) {
    const int buf = kt & 1;
    if (kt < 5) {
      // prefetch tile kt+1 into the other buffer (safe: its readers finished
      // before the barrier that ended iter kt-1)
#pragma unroll
      for (int i = 0; i < 4; ++i) {
        gl_lds16(ga[i], (char*)As[buf ^ 1] + lof[i]);
        gl_lds16(gb[i], (char*)Bs[buf ^ 1] + lof[i]);
        ga[i] += 64; gb[i] += 64;
      }
      asm volatile("s_waitcnt vmcnt(8)" ::: "memory");  // tile kt landed; kt+1 in flight
    } else {
      asm volatile("s_waitcnt vmcnt(0)" ::: "memory");
    }
    __builtin_amdgcn_s_barrier();           // all waves' tile-kt loads landed
    __builtin_amdgcn_sched_barrier(0);      // pin: no ds_read above the barrier
#pragma unroll
    for (int kk = 0; kk < 2; ++kk) {
      bf16x8 af[4], bg[4];
#pragma unroll
      for (int f = 0; f < 4; ++f) {
        af[f] = *reinterpret_cast<const bf16x8*>((const char*)As[buf] + offA[kk][f]);
        bg[f] = *reinterpret_cast<const bf16x8*>((const char*)Bs[buf] + offB[kk][f]);
      }
#pragma unroll
      for (int i = 0; i < 4; ++i)
#pragma unroll
        for (int j = 0; j < 4; ++j)
          acc[i][j] = __builtin_amdgcn_mfma_f32_16x16x32_bf16(af[i], bg[j], acc[i][j], 0, 0, 0);
    }
    __builtin_amdgcn_s_barrier();           // all waves done reading buf -> overwritable
    __builtin_amdgcn_sched_barrier(0);      // pin: no next-iter gl_lds above it
  }

  // epilogue: d2 = a2 + b2 - 2*dot ; per-row min over this block's 128 cols
  u64* sh = reinterpret_cast<u64*>(As);  // 128 rows x 2 wc slots = 2KB scratch

#pragma unroll
  for (int fm = 0; fm < 4; ++fm) {
#pragma unroll
    for (int j = 0; j < 4; ++j) {
      const int rowL = wr * 64 + fm * 16 + rg * 4 + j;  // C/D: col=lane&15, row=(lane>>4)*4+reg
      const float ar = a2[n0 + rowL];
      float best = INFF;
      int bidx = 0x7FFFFFFF;
#pragma unroll
      for (int fn = 0; fn < 4; ++fn) {
        const float d2 = ar + bc[fn] - 2.0f * acc[fm][fn][j];
        const int col = m0 + wc * 64 + fn * 16 + cl;
        if (d2 < best || (d2 == best && col < bidx)) { best = d2; bidx = col; }
      }
#pragma unroll
      for (int msk = 1; msk < 16; msk <<= 1) {
        const float ov = __shfl_xor(best, msk);
        const int oi = __shfl_xor(bidx, msk);
        if (ov < best || (ov == best && oi < bidx)) { best = ov; bidx = oi; }
      }
      if (cl == 0) sh[rowL * 2 + wc] = ((u64)__float_as_uint(fmaxf(best, 0.0f)) << 32) | (unsigned)bidx;
    }
  }
  __syncthreads();
  if (wc == 0) {
    const int row = wr * 64 + lane;
    const u64 v0 = sh[row * 2], v1 = sh[row * 2 + 1];
    atomicMin(&packed[n0 + row], v0 < v1 ? v0 : v1);
  }
}

// ---------------- candidate rows near the max ----------------
__global__ __launch_bounds__(256) void cand_kernel(const u64* __restrict__ packed,
                                                   int* __restrict__ cand) {
  const int tid = threadIdx.x;
  float mx = -1.f;
  for (int n = tid; n < NP; n += 256) {
    const float v = __uint_as_float((unsigned)(packed[n] >> 32));
    mx = fmaxf(mx, v);
  }
#pragma unroll
  for (int m = 1; m < 64; m <<= 1) mx = fmaxf(mx, __shfl_xor(mx, m));
  __shared__ float wmax[4];
  __shared__ float smax;
  if ((tid & 63) == 0) wmax[tid >> 6] = mx;
  __syncthreads();
  if (tid == 0) {
    smax = fmaxf(fmaxf(wmax[0], wmax[1]), fmaxf(wmax[2], wmax[3]));
    cand[0] = 0;
  }
  __syncthreads();
  const float thr = smax - 4.0f;  // d^2 margin >> bf16 error
  for (int n = tid; n < NP; n += 256) {
    const float v = __uint_as_float((unsigned)(packed[n] >> 32));
    if (v >= thr) {
      const int slot = atomicAdd(&cand[0], 1);
      if (slot < 256) cand[1 + slot] = n;
    }
  }
}

// ---------------- exact fp32 refinement: block owns 32 lib rows ----------------
__global__ __launch_bounds__(256) void refine_kernel(const float* __restrict__ patch,
                                                     const float* __restrict__ lib,
                                                     const int* __restrict__ cand,
                                                     u64* __restrict__ refined) {
  const int cnt = min(cand[0], 256);
  const int tid = threadIdx.x, lane = tid & 63, w = tid >> 6;
  const int base = blockIdx.x * 32;  // 2048 blocks
  __shared__ float a[8][DIM];        // 12 KB candidate staging
  __shared__ u64 rb[8][4];

  for (int g0 = 0; g0 < cnt; g0 += 8) {
    const int gc = min(cnt - g0, 8);
    for (int i = tid; i < gc * DIM; i += 256) {
      const int c = i / DIM, e = i - c * DIM;
      a[c][e] = patch[(size_t)cand[1 + g0 + c] * DIM + e];
    }
    __syncthreads();

    u64 wbest[8];
#pragma unroll
    for (int c = 0; c < 8; ++c) wbest[c] = ~0ull;

    for (int it = 0; it < 8; ++it) {
      const int m = base + w * 8 + it;
      float lr[6];
#pragma unroll
      for (int j = 0; j < 3; ++j) {
        const float2 v = *reinterpret_cast<const float2*>(lib + (size_t)m * DIM + j * 128 + lane * 2);
        lr[j * 2] = v.x; lr[j * 2 + 1] = v.y;
      }
#pragma unroll
      for (int c = 0; c < 8; ++c) {
        if (c >= gc) break;
        float s = 0.f;
#pragma unroll
        for (int j = 0; j < 3; ++j) {
          const float d0 = lr[j * 2] - a[c][j * 128 + lane * 2];
          const float d1 = lr[j * 2 + 1] - a[c][j * 128 + lane * 2 + 1];
          s += d0 * d0 + d1 * d1;
        }
#pragma unroll
        for (int msk = 1; msk < 64; msk <<= 1) s += __shfl_xor(s, msk);
        const u64 p = ((u64)__float_as_uint(s) << 32) | (unsigned)m;
        wbest[c] = p < wbest[c] ? p : wbest[c];
      }
    }
    if (lane == 0) {
#pragma unroll
      for (int c = 0; c < 8; ++c)
        if (c < gc) rb[c][w] = wbest[c];
    }
    __syncthreads();
    if (tid < gc) {
      u64 b = rb[tid][0];
#pragma unroll
      for (int k = 1; k < 4; ++k) b = rb[tid][k] < b ? rb[tid][k] : b;
      atomicMin(&refined[g0 + tid], b);
    }
    __syncthreads();
  }
}

// ---------------- pick exact argmax row ----------------
__global__ __launch_bounds__(256) void pick_kernel(const u64* __restrict__ refined,
                                                   const int* __restrict__ cand,
                                                   int* __restrict__ scal_i,
                                                   float* __restrict__ scal_f) {
  const int tid = threadIdx.x, lane = tid & 63, w = tid >> 6;
  const int cnt = min(cand[0], 256);
  float v = -1.f;
  int nrow = 0x7FFFFFFF;
  int mi = 0;
  if (tid < cnt) {
    const u64 p = refined[tid];
    v = __uint_as_float((unsigned)(p >> 32));
    nrow = cand[1 + tid];
    mi = (int)(unsigned)p;
  }
#pragma unroll
  for (int msk = 1; msk < 64; msk <<= 1) {
    const float ov = __shfl_xor(v, msk);
    const int on = __shfl_xor(nrow, msk);
    const int om = __shfl_xor(mi, msk);
    if (ov > v || (ov == v && on < nrow)) { v = ov; nrow = on; mi = om; }
  }
  __shared__ float sv[4]; __shared__ int sn[4]; __shared__ int sm[4];
  if (lane == 0) { sv[w] = v; sn[w] = nrow; sm[w] = mi; }
  __syncthreads();
  if (tid == 0) {
    for (int k = 1; k < 4; ++k)
      if (sv[k] > v || (sv[k] == v && sn[k] < nrow)) { v = sv[k]; nrow = sn[k]; mi = sm[k]; }
    scal_i[0] = nrow;       // s_idx
    scal_i[1] = mi;         // m_star index
    scal_f[0] = sqrtf(fmaxf(v, 0.f));  // s_star
  }
}

// ---------------- fused w_dist + per-block top-3 (block owns 32 rows) ----------------
__device__ __forceinline__ void ins3u(u64 x, u64* v) {
  if (x < v[2]) {
    v[2] = x;
    if (v[2] < v[1]) { u64 t = v[1]; v[1] = v[2]; v[2] = t; }
    if (v[1] < v[0]) { u64 t = v[0]; v[0] = v[1]; v[1] = t; }
  }
}

__global__ __launch_bounds__(256) void wtop_kernel(const float* __restrict__ lib,
                                                   const int* __restrict__ scal_i,
                                                   u64* __restrict__ t3) {
  __shared__ float a[DIM];
  __shared__ u64 sv[12];
  const int tid = threadIdx.x, lane = tid & 63, w = tid >> 6;
  const int ms = scal_i[1];
  for (int i = tid; i < DIM; i += 256) a[i] = lib[(size_t)ms * DIM + i];
  __syncthreads();
  const int base = blockIdx.x * 32;  // 2048 blocks
  u64 v[3] = {~0ull, ~0ull, ~0ull};
  for (int it = 0; it < 8; ++it) {
    const int m = base + w * 8 + it;
    float s = 0.f;
#pragma unroll
    for (int j = 0; j < 3; ++j) {
      const float2 lv = *reinterpret_cast<const float2*>(lib + (size_t)m * DIM + j * 128 + lane * 2);
      const float d0 = lv.x - a[j * 128 + lane * 2];
      const float d1 = lv.y - a[j * 128 + lane * 2 + 1];
      s += d0 * d0 + d1 * d1;
    }
#pragma unroll
    for (int msk = 1; msk < 64; msk <<= 1) s += __shfl_xor(s, msk);
    ins3u(((u64)__float_as_uint(s) << 32) | (unsigned)m, v);  // wave-uniform
  }
  if (lane == 0) {
#pragma unroll
    for (int k = 0; k < 3; ++k) sv[w * 3 + k] = v[k];
  }
  __syncthreads();
  if (tid == 0) {
    u64 fv[3] = {~0ull, ~0ull, ~0ull};
    for (int k = 0; k < 12; ++k) ins3u(sv[k], fv);
#pragma unroll
    for (int k = 0; k < 3; ++k) t3[blockIdx.x * 3 + k] = fv[k];
  }
}

// ---------------- stage-2 top-3 + final score ----------------
__global__ __launch_bounds__(256) void final_kernel(const u64* __restrict__ t3,
                                                    const float* __restrict__ patch,
                                                    const float* __restrict__ lib,
                                                    const int* __restrict__ scal_i,
                                                    const float* __restrict__ scal_f,
                                                    float* __restrict__ out) {
  const int tid = threadIdx.x, lane = tid & 63, w = tid >> 6;
  u64 v[3] = {~0ull, ~0ull, ~0ull};
  for (int i = tid; i < 6144; i += 256) ins3u(t3[i], v);
#pragma unroll
  for (int msk = 1; msk < 64; msk <<= 1) {
    u64 o0 = __shfl_xor(v[0], msk);
    u64 o1 = __shfl_xor(v[1], msk);
    u64 o2 = __shfl_xor(v[2], msk);
    ins3u(o0, v); ins3u(o1, v); ins3u(o2, v);
  }
  __shared__ u64 sv[12];
  __shared__ int nn[2]; __shared__ float kk[2];
  if (lane == 0) {
#pragma unroll
    for (int k = 0; k < 3; ++k) sv[w * 3 + k] = v[k];
  }
  __syncthreads();
  if (tid == 0) {
    u64 fv[3] = {~0ull, ~0ull, ~0ull};
    for (int k = 0; k < 12; ++k) ins3u(sv[k], fv);
    nn[0] = (int)(unsigned)fv[1];  // skip fv[0] == m_star itself
    nn[1] = (int)(unsigned)fv[2];
  }
  __syncthreads();
  if (w < 2) {
    const int s_idx = scal_i[0];
    const int nnx = nn[w];
    float s = 0.f;
#pragma unroll
    for (int k = 0; k < 6; ++k) {
      const float d = patch[(size_t)s_idx * DIM + lane + k * 64] - lib[(size_t)nnx * DIM + lane + k * 64];
      s += d * d;
    }
#pragma unroll
    for (int msk = 1; msk < 64; msk <<= 1) s += __shfl_xor(s, msk);
    if (lane == 0) kk[w] = sqrtf(s);
  }
  __syncthreads();
  if (tid == 0) {
    const float s_star = scal_f[0];
    const float Ds = 19.59591794f;  // sqrt(384)
    const float wt = 1.0f - expf(s_star / Ds) / (expf(kk[0] / Ds) + expf(kk[1] / Ds));
    out[0] = wt * s_star;
  }
}

// ---------------- score map: resize (reads packed directly) + blur ----------------
__device__ __forceinline__ float mval(const u64* packed, int n) {
  return sqrtf(fmaxf(__uint_as_float((unsigned)(packed[n] >> 32)), 0.f));
}

__global__ __launch_bounds__(256) void resize_kernel(const u64* __restrict__ packed,
                                                     float* __restrict__ t1) {
  const int idx = blockIdx.x * 256 + threadIdx.x;  // 262144
  const int x = idx & 511, y = idx >> 9;
  const float sy = y * 0.125f - 0.4375f;
  const float sx = x * 0.125f - 0.4375f;
  const int y0 = (int)floorf(sy); const float fy = sy - (float)y0;
  const int x0 = (int)floorf(sx); const float fx = sx - (float)x0;
  const int ya = max(y0, 0), yb = min(y0 + 1, 63);
  const int xa = max(x0, 0), xb = min(x0 + 1, 63);
  const float v00 = mval(packed, ya * 64 + xa), v01 = mval(packed, ya * 64 + xb);
  const float v10 = mval(packed, yb * 64 + xa), v11 = mval(packed, yb * 64 + xb);
  t1[idx] = (1.f - fy) * ((1.f - fx) * v00 + fx * v01) + fy * ((1.f - fx) * v10 + fx * v11);
}

__device__ __constant__ float BW[9] = {
    0.0816741424f, 0.1016453893f, 0.1188358540f, 0.1305155396f, 0.1346581512f,
    0.1305155396f, 0.1188358540f, 0.1016453893f, 0.0816741424f};

__global__ __launch_bounds__(256) void blurv_kernel(const float* __restrict__ t1,
                                                    float* __restrict__ t2) {
  const int idx = blockIdx.x * 256 + threadIdx.x;
  const int x = idx & 511, y = idx >> 9;
  float s = 0.f;
#pragma unroll
  for (int k = -4; k <= 4; ++k) {
    const int yy = y + k;
    if (yy >= 0 && yy < 512) s += BW[k + 4] * t1[yy * 512 + x];
  }
  t2[idx] = s;
}

__global__ __launch_bounds__(256) void blurh_kernel(const float* __restrict__ t2,
                                                    float* __restrict__ out) {
  const int idx = blockIdx.x * 256 + threadIdx.x;
  const int x = idx & 511, y = idx >> 9;
  float s = 0.f;
#pragma unroll
  for (int k = -4; k <= 4; ++k) {
    const int xx = x + k;
    if (xx >= 0 && xx < 512) s += BW[k + 4] * t2[y * 512 + xx];
  }
  out[idx] = s;
}

extern "C" void kernel_launch(void* const* d_in, const int* in_sizes, int n_in,
                              void* d_out, int out_size, void* d_ws, size_t ws_size,
                              hipStream_t stream) {
  const float* patch = (const float*)d_in[0];
  const float* lib = (const float*)d_in[1];
  float* out = (float*)d_out;

  char* ws = (char*)d_ws;
  size_t off = 0;
  auto alloc = [&](size_t bytes) {
    void* p = ws + off;
    off += (bytes + 255) & ~(size_t)255;
    return p;
  };
  u16* Abf = (u16*)alloc((size_t)NP * DIM * 2);
  u16* Bbf = (u16*)alloc((size_t)ML * DIM * 2);
  float* a2 = (float*)alloc(NP * 4);
  float* b2 = (float*)alloc(ML * 4);
  u64* packed = (u64*)alloc(NP * 8);
  u64* refined = (u64*)alloc(256 * 8);
  int* cand = (int*)alloc(257 * 4);
  int* scal_i = (int*)alloc(64);
  float* scal_f = (float*)alloc(64);
  u64* t3 = (u64*)alloc(2048 * 3 * 8);
  float* t1 = (float*)alloc(512 * 512 * 4);
  float* t2 = (float*)alloc(512 * 512 * 4);

  hipMemsetAsync(packed, 0xFF, NP * 8, stream);
  hipMemsetAsync(refined, 0xFF, 256 * 8, stream);

  prep_kernel<<<NP / 4, 256, 0, stream>>>(patch, Abf, a2);
  prep_kernel<<<ML / 4, 256, 0, stream>>>(lib, Bbf, b2);
  gemm_min_kernel<<<16384, 256, 0, stream>>>(Abf, Bbf, a2, b2, packed);
  cand_kernel<<<1, 256, 0, stream>>>(packed, cand);
  refine_kernel<<<2048, 256, 0, stream>>>(patch, lib, cand, refined);
  pick_kernel<<<1, 256, 0, stream>>>(refined, cand, scal_i, scal_f);
  wtop_kernel<<<2048, 256, 0, stream>>>(lib, scal_i, t3);
  final_kernel<<<1, 256, 0, stream>>>(t3, patch, lib, scal_i, scal_f, out);
  resize_kernel<<<1024, 256, 0, stream>>>(packed, t1);
  blurv_kernel<<<1024, 256, 0, stream>>>(t1, t2);
  blurh_kernel<<<1024, 256, 0, stream>>>(t2, out + 1);
}

// Round 5
// 362.410 us; speedup vs baseline: 5.0190x; 1.7274x over previous
//
#include <hip/hip_runtime.h>

#define NP 4096
#define DIM 384
#define ML 65536
#define INFF 3.402823466e38f

typedef short bf16x8 __attribute__((ext_vector_type(8)));
typedef float f32x4 __attribute__((ext_vector_type(4)));
typedef unsigned short u16;
typedef unsigned long long u64;

typedef __attribute__((address_space(1))) unsigned int as1_u32;
typedef __attribute__((address_space(3))) unsigned int as3_u32;

__device__ __forceinline__ void gl_lds16(const void* g, void* l) {
  __builtin_amdgcn_global_load_lds((const as1_u32*)g, (as3_u32*)l, 16, 0, 0);
}

__device__ __forceinline__ u16 f2bf(float x) {
  unsigned u = __float_as_uint(x);
  u += 0x7FFFu + ((u >> 16) & 1u);
  return (u16)(u >> 16);
}

// ---------------- prep: fp32 -> bf16 + row sumsq (wave per row, both inputs) ----------------
__global__ __launch_bounds__(256) void prep_kernel(const float* __restrict__ patch,
                                                   const float* __restrict__ lib,
                                                   u16* __restrict__ Abf,
                                                   u16* __restrict__ Bbf,
                                                   float* __restrict__ a2,
                                                   float* __restrict__ b2) {
  const int row = blockIdx.x * 4 + (threadIdx.x >> 6);
  const int lane = threadIdx.x & 63;
  const float* src;
  u16* dst;
  float* nrm;
  int r;
  if (row < NP) { src = patch; dst = Abf; nrm = a2; r = row; }
  else          { src = lib;   dst = Bbf; nrm = b2; r = row - NP; }
  float s = 0.f;
#pragma unroll
  for (int j = 0; j < 3; ++j) {
    const float2 v = *reinterpret_cast<const float2*>(src + (size_t)r * DIM + j * 128 + lane * 2);
    s += v.x * v.x + v.y * v.y;
    const unsigned p = ((unsigned)f2bf(v.y) << 16) | (unsigned)f2bf(v.x);
    *reinterpret_cast<unsigned*>(dst + (size_t)r * DIM + j * 128 + lane * 2) = p;
  }
#pragma unroll
  for (int m = 1; m < 64; m <<= 1) s += __shfl_xor(s, m);
  if (lane == 0) nrm[r] = s;
}

// ---- fused bf16 GEMM + row-min (T2 swizzle + T1 remap + dbuf + transposed acc) ----
__global__ __launch_bounds__(256) void gemm_min_kernel(const u16* __restrict__ Abf,
                                                       const u16* __restrict__ Bbf,
                                                       const float* __restrict__ a2,
                                                       const float* __restrict__ b2,
                                                       u64* __restrict__ packed) {
  __shared__ __align__(16) u16 As[2][8192];
  __shared__ __align__(16) u16 Bs[2][8192];
  const int tid = threadIdx.x;
  const int lane = tid & 63;
  const int w = tid >> 6;
  const int wr = w >> 1, wc = w & 1;

  const int orig = blockIdx.x;
  const int logical = (orig & 7) * 2048 + (orig >> 3);
  const int xt = logical & 31;
  const int yt = logical >> 5;
  const int n0 = xt * 128;   // patch rows
  const int m0 = yt * 128;   // lib rows (output cols)
  const int cl = lane & 15, rg = lane >> 4;

  // staging addresses (kt-invariant, advanced by +=64 per tile)
  const u16* ga[4]; const u16* gb[4]; int lof[4];
#pragma unroll
  for (int i = 0; i < 4; ++i) {
    const int P = i * 4096 + tid * 16;     // linear LDS dest byte
    const int r = P >> 7;                  // tile row (128B per row)
    const int L = P ^ ((r & 7) << 4);      // inverse-swizzled source offset
    const int c = (L & 127) >> 1;          // ushort col within row
    lof[i] = P;
    ga[i] = Abf + (size_t)(n0 + r) * DIM + c;
    gb[i] = Bbf + (size_t)(m0 + r) * DIM + c;
  }

  // fragment byte offsets (kt-invariant)
  int offA[2][4], offB[2][4];
#pragma unroll
  for (int kk = 0; kk < 2; ++kk)
#pragma unroll
    for (int f = 0; f < 4; ++f) {
      offA[kk][f] = (((wr * 64 + f * 16 + cl) * 128) + kk * 64 + rg * 16) ^ ((cl & 7) << 4);
      offB[kk][f] = (((wc * 64 + f * 16 + cl) * 128) + kk * 64 + rg * 16) ^ ((cl & 7) << 4);
    }

  f32x4 acc[4][4] = {};

  // prologue: stage tile 0 into buf 0
#pragma unroll
  for (int i = 0; i < 4; ++i) {
    gl_lds16(ga[i], (char*)As[0] + lof[i]);
    gl_lds16(gb[i], (char*)Bs[0] + lof[i]);
    ga[i] += 64; gb[i] += 64;
  }

#pragma unroll
  for (int kt = 0; kt < 6; ++kt) {
    const int buf = kt & 1;
    if (kt < 5) {
#pragma unroll
      for (int i = 0; i < 4; ++i) {
        gl_lds16(ga[i], (char*)As[buf ^ 1] + lof[i]);
        gl_lds16(gb[i], (char*)Bs[buf ^ 1] + lof[i]);
        ga[i] += 64; gb[i] += 64;
      }
      asm volatile("s_waitcnt vmcnt(8)" ::: "memory");  // tile kt landed; kt+1 in flight
    } else {
      asm volatile("s_waitcnt vmcnt(0)" ::: "memory");
    }
    __builtin_amdgcn_s_barrier();
    __builtin_amdgcn_sched_barrier(0);
#pragma unroll
    for (int kk = 0; kk < 2; ++kk) {
      bf16x8 af[4], bg[4];
#pragma unroll
      for (int f = 0; f < 4; ++f) {
        af[f] = *reinterpret_cast<const bf16x8*>((const char*)As[buf] + offA[kk][f]);
        bg[f] = *reinterpret_cast<const bf16x8*>((const char*)Bs[buf] + offB[kk][f]);
      }
      // swapped operands: D[lib][patch] -> patch row is cl in C/D layout
#pragma unroll
      for (int i = 0; i < 4; ++i)
#pragma unroll
        for (int j = 0; j < 4; ++j)
          acc[i][j] = __builtin_amdgcn_mfma_f32_16x16x32_bf16(bg[i], af[j], acc[i][j], 0, 0, 0);
    }
    __builtin_amdgcn_s_barrier();
    __builtin_amdgcn_sched_barrier(0);
  }

  // epilogue: lane (cl,rg), frag (i,j), reg r holds dot for
  //   patch row = n0 + wr*64 + j*16 + cl ; lib col = m0 + wc*64 + i*16 + rg*4 + r
  const int colb = m0 + wc * 64 + rg * 4;
  float bc[4][4];
#pragma unroll
  for (int i = 0; i < 4; ++i)
#pragma unroll
    for (int r = 0; r < 4; ++r) bc[i][r] = b2[colb + i * 16 + r];

  u64* sh = reinterpret_cast<u64*>(As);  // 128 rows x 2 wc slots = 2KB scratch

#pragma unroll
  for (int j = 0; j < 4; ++j) {
    const int prow = wr * 64 + j * 16 + cl;
    const float ar = a2[n0 + prow];
    u64 best = ~0ull;
#pragma unroll
    for (int i = 0; i < 4; ++i)
#pragma unroll
      for (int r = 0; r < 4; ++r) {
        const float d2 = fmaxf(ar + bc[i][r] - 2.0f * acc[i][j][r], 0.0f);
        const u64 p = ((u64)__float_as_uint(d2) << 32) | (unsigned)(colb + i * 16 + r);
        best = p < best ? p : best;
      }
    const u64 o1 = __shfl_xor(best, 16); best = o1 < best ? o1 : best;
    const u64 o2 = __shfl_xor(best, 32); best = o2 < best ? o2 : best;
    if (rg == 0) sh[prow * 2 + wc] = best;
  }
  __syncthreads();
  if (wc == 0) {
    const int row = wr * 64 + lane;
    const u64 v0 = sh[row * 2], v1 = sh[row * 2 + 1];
    atomicMin(&packed[n0 + row], v0 < v1 ? v0 : v1);
  }
}

// ---------------- candidate rows near the max ----------------
__global__ __launch_bounds__(256) void cand_kernel(const u64* __restrict__ packed,
                                                   int* __restrict__ cand) {
  const int tid = threadIdx.x;
  float mx = -1.f;
  for (int n = tid; n < NP; n += 256) {
    const float v = __uint_as_float((unsigned)(packed[n] >> 32));
    mx = fmaxf(mx, v);
  }
#pragma unroll
  for (int m = 1; m < 64; m <<= 1) mx = fmaxf(mx, __shfl_xor(mx, m));
  __shared__ float wmax[4];
  __shared__ float smax;
  if ((tid & 63) == 0) wmax[tid >> 6] = mx;
  __syncthreads();
  if (tid == 0) {
    smax = fmaxf(fmaxf(wmax[0], wmax[1]), fmaxf(wmax[2], wmax[3]));
    cand[0] = 0;
  }
  __syncthreads();
  const float thr = smax - 4.0f;  // d^2 margin >> bf16 error
  for (int n = tid; n < NP; n += 256) {
    const float v = __uint_as_float((unsigned)(packed[n] >> 32));
    if (v >= thr) {
      const int slot = atomicAdd(&cand[0], 1);
      if (slot < 256) cand[1 + slot] = n;
    }
  }
}

// ---------------- exact fp32 refinement: block owns 32 lib rows ----------------
__global__ __launch_bounds__(256) void refine_kernel(const float* __restrict__ patch,
                                                     const float* __restrict__ lib,
                                                     const int* __restrict__ cand,
                                                     u64* __restrict__ refined) {
  const int cnt = min(cand[0], 256);
  const int tid = threadIdx.x, lane = tid & 63, w = tid >> 6;
  const int base = blockIdx.x * 32;  // 2048 blocks
  __shared__ float a[8][DIM];        // 12 KB candidate staging
  __shared__ u64 rb[8][4];

  for (int g0 = 0; g0 < cnt; g0 += 8) {
    const int gc = min(cnt - g0, 8);
    for (int i = tid; i < gc * DIM; i += 256) {
      const int c = i / DIM, e = i - c * DIM;
      a[c][e] = patch[(size_t)cand[1 + g0 + c] * DIM + e];
    }
    __syncthreads();

    u64 wbest[8];
#pragma unroll
    for (int c = 0; c < 8; ++c) wbest[c] = ~0ull;

    for (int it = 0; it < 8; ++it) {
      const int m = base + w * 8 + it;
      float lr[6];
#pragma unroll
      for (int j = 0; j < 3; ++j) {
        const float2 v = *reinterpret_cast<const float2*>(lib + (size_t)m * DIM + j * 128 + lane * 2);
        lr[j * 2] = v.x; lr[j * 2 + 1] = v.y;
      }
#pragma unroll
      for (int c = 0; c < 8; ++c) {
        if (c >= gc) break;
        float s = 0.f;
#pragma unroll
        for (int j = 0; j < 3; ++j) {
          const float d0 = lr[j * 2] - a[c][j * 128 + lane * 2];
          const float d1 = lr[j * 2 + 1] - a[c][j * 128 + lane * 2 + 1];
          s += d0 * d0 + d1 * d1;
        }
#pragma unroll
        for (int msk = 1; msk < 64; msk <<= 1) s += __shfl_xor(s, msk);
        const u64 p = ((u64)__float_as_uint(s) << 32) | (unsigned)m;
        wbest[c] = p < wbest[c] ? p : wbest[c];
      }
    }
    if (lane == 0) {
#pragma unroll
      for (int c = 0; c < 8; ++c)
        if (c < gc) rb[c][w] = wbest[c];
    }
    __syncthreads();
    if (tid < gc) {
      u64 b = rb[tid][0];
#pragma unroll
      for (int k = 1; k < 4; ++k) b = rb[tid][k] < b ? rb[tid][k] : b;
      atomicMin(&refined[g0 + tid], b);
    }
    __syncthreads();
  }
}

// ---------------- pick exact argmax row ----------------
__global__ __launch_bounds__(256) void pick_kernel(const u64* __restrict__ refined,
                                                   const int* __restrict__ cand,
                                                   int* __restrict__ scal_i,
                                                   float* __restrict__ scal_f) {
  const int tid = threadIdx.x, lane = tid & 63, w = tid >> 6;
  const int cnt = min(cand[0], 256);
  float v = -1.f;
  int nrow = 0x7FFFFFFF;
  int mi = 0;
  if (tid < cnt) {
    const u64 p = refined[tid];
    v = __uint_as_float((unsigned)(p >> 32));
    nrow = cand[1 + tid];
    mi = (int)(unsigned)p;
  }
#pragma unroll
  for (int msk = 1; msk < 64; msk <<= 1) {
    const float ov = __shfl_xor(v, msk);
    const int on = __shfl_xor(nrow, msk);
    const int om = __shfl_xor(mi, msk);
    if (ov > v || (ov == v && on < nrow)) { v = ov; nrow = on; mi = om; }
  }
  __shared__ float sv[4]; __shared__ int sn[4]; __shared__ int sm[4];
  if (lane == 0) { sv[w] = v; sn[w] = nrow; sm[w] = mi; }
  __syncthreads();
  if (tid == 0) {
    for (int k = 1; k < 4; ++k)
      if (sv[k] > v || (sv[k] == v && sn[k] < nrow)) { v = sv[k]; nrow = sn[k]; mi = sm[k]; }
    scal_i[0] = nrow;       // s_idx
    scal_i[1] = mi;         // m_star index
    scal_f[0] = sqrtf(fmaxf(v, 0.f));  // s_star
  }
}

// ---------------- fused w_dist + per-block top-3 (block owns 32 rows) ----------------
__device__ __forceinline__ void ins3u(u64 x, u64* v) {
  if (x < v[2]) {
    v[2] = x;
    if (v[2] < v[1]) { u64 t = v[1]; v[1] = v[2]; v[2] = t; }
    if (v[1] < v[0]) { u64 t = v[0]; v[0] = v[1]; v[1] = t; }
  }
}

__global__ __launch_bounds__(256) void wtop_kernel(const float* __restrict__ lib,
                                                   const int* __restrict__ scal_i,
                                                   u64* __restrict__ t3) {
  __shared__ float a[DIM];
  __shared__ u64 sv[12];
  const int tid = threadIdx.x, lane = tid & 63, w = tid >> 6;
  const int ms = scal_i[1];
  for (int i = tid; i < DIM; i += 256) a[i] = lib[(size_t)ms * DIM + i];
  __syncthreads();
  const int base = blockIdx.x * 32;  // 2048 blocks
  u64 v[3] = {~0ull, ~0ull, ~0ull};
  for (int it = 0; it < 8; ++it) {
    const int m = base + w * 8 + it;
    float s = 0.f;
#pragma unroll
    for (int j = 0; j < 3; ++j) {
      const float2 lv = *reinterpret_cast<const float2*>(lib + (size_t)m * DIM + j * 128 + lane * 2);
      const float d0 = lv.x - a[j * 128 + lane * 2];
      const float d1 = lv.y - a[j * 128 + lane * 2 + 1];
      s += d0 * d0 + d1 * d1;
    }
#pragma unroll
    for (int msk = 1; msk < 64; msk <<= 1) s += __shfl_xor(s, msk);
    ins3u(((u64)__float_as_uint(s) << 32) | (unsigned)m, v);  // wave-uniform
  }
  if (lane == 0) {
#pragma unroll
    for (int k = 0; k < 3; ++k) sv[w * 3 + k] = v[k];
  }
  __syncthreads();
  if (tid == 0) {
    u64 fv[3] = {~0ull, ~0ull, ~0ull};
    for (int k = 0; k < 12; ++k) ins3u(sv[k], fv);
#pragma unroll
    for (int k = 0; k < 3; ++k) t3[blockIdx.x * 3 + k] = fv[k];
  }
}

// ---------------- stage-2 top-3 + final score ----------------
__global__ __launch_bounds__(256) void final_kernel(const u64* __restrict__ t3,
                                                    const float* __restrict__ patch,
                                                    const float* __restrict__ lib,
                                                    const int* __restrict__ scal_i,
                                                    const float* __restrict__ scal_f,
                                                    float* __restrict__ out) {
  const int tid = threadIdx.x, lane = tid & 63, w = tid >> 6;
  u64 v[3] = {~0ull, ~0ull, ~0ull};
  for (int i = tid; i < 6144; i += 256) ins3u(t3[i], v);
#pragma unroll
  for (int msk = 1; msk < 64; msk <<= 1) {
    u64 o0 = __shfl_xor(v[0], msk);
    u64 o1 = __shfl_xor(v[1], msk);
    u64 o2 = __shfl_xor(v[2], msk);
    ins3u(o0, v); ins3u(o1, v); ins3u(o2, v);
  }
  __shared__ u64 sv[12];
  __shared__ int nn[2]; __shared__ float kk[2];
  if (lane == 0) {
#pragma unroll
    for (int k = 0; k < 3; ++k) sv[w * 3 + k] = v[k];
  }
  __syncthreads();
  if (tid == 0) {
    u64 fv[3] = {~0ull, ~0ull, ~0ull};
    for (int k = 0; k < 12; ++k) ins3u(sv[k], fv);
    nn[0] = (int)(unsigned)fv[1];  // skip fv[0] == m_star itself
    nn[1] = (int)(unsigned)fv[2];
  }
  __syncthreads();
  if (w < 2) {
    const int s_idx = scal_i[0];
    const int nnx = nn[w];
    float s = 0.f;
#pragma unroll
    for (int k = 0; k < 6; ++k) {
      const float d = patch[(size_t)s_idx * DIM + lane + k * 64] - lib[(size_t)nnx * DIM + lane + k * 64];
      s += d * d;
    }
#pragma unroll
    for (int msk = 1; msk < 64; msk <<= 1) s += __shfl_xor(s, msk);
    if (lane == 0) kk[w] = sqrtf(s);
  }
  __syncthreads();
  if (tid == 0) {
    const float s_star = scal_f[0];
    const float Ds = 19.59591794f;  // sqrt(384)
    const float wt = 1.0f - expf(s_star / Ds) / (expf(kk[0] / Ds) + expf(kk[1] / Ds));
    out[0] = wt * s_star;
  }
}

// ---------------- score map: resize (reads packed directly) + blur ----------------
__device__ __forceinline__ float mval(const u64* packed, int n) {
  return sqrtf(fmaxf(__uint_as_float((unsigned)(packed[n] >> 32)), 0.f));
}

__global__ __launch_bounds__(256) void resize_kernel(const u64* __restrict__ packed,
                                                     float* __restrict__ t1) {
  const int idx = blockIdx.x * 256 + threadIdx.x;  // 262144
  const int x = idx & 511, y = idx >> 9;
  const float sy = y * 0.125f - 0.4375f;
  const float sx = x * 0.125f - 0.4375f;
  const int y0 = (int)floorf(sy); const float fy = sy - (float)y0;
  const int x0 = (int)floorf(sx); const float fx = sx - (float)x0;
  const int ya = max(y0, 0), yb = min(y0 + 1, 63);
  const int xa = max(x0, 0), xb = min(x0 + 1, 63);
  const float v00 = mval(packed, ya * 64 + xa), v01 = mval(packed, ya * 64 + xb);
  const float v10 = mval(packed, yb * 64 + xa), v11 = mval(packed, yb * 64 + xb);
  t1[idx] = (1.f - fy) * ((1.f - fx) * v00 + fx * v01) + fy * ((1.f - fx) * v10 + fx * v11);
}

__device__ __constant__ float BW[9] = {
    0.0816741424f, 0.1016453893f, 0.1188358540f, 0.1305155396f, 0.1346581512f,
    0.1305155396f, 0.1188358540f, 0.1016453893f, 0.0816741424f};

__global__ __launch_bounds__(256) void blurv_kernel(const float* __restrict__ t1,
                                                    float* __restrict__ t2) {
  const int idx = blockIdx.x * 256 + threadIdx.x;
  const int x = idx & 511, y = idx >> 9;
  float s = 0.f;
#pragma unroll
  for (int k = -4; k <= 4; ++k) {
    const int yy = y + k;
    if (yy >= 0 && yy < 512) s += BW[k + 4] * t1[yy * 512 + x];
  }
  t2[idx] = s;
}

__global__ __launch_bounds__(256) void blurh_kernel(const float* __restrict__ t2,
                                                    float* __restrict__ out) {
  const int idx = blockIdx.x * 256 + threadIdx.x;
  const int x = idx & 511, y = idx >> 9;
  float s = 0.f;
#pragma unroll
  for (int k = -4; k <= 4; ++k) {
    const int xx = x + k;
    if (xx >= 0 && xx < 512) s += BW[k + 4] * t2[y * 512 + xx];
  }
  out[idx] = s;
}

extern "C" void kernel_launch(void* const* d_in, const int* in_sizes, int n_in,
                              void* d_out, int out_size, void* d_ws, size_t ws_size,
                              hipStream_t stream) {
  const float* patch = (const float*)d_in[0];
  const float* lib = (const float*)d_in[1];
  float* out = (float*)d_out;

  char* ws = (char*)d_ws;
  size_t off = 0;
  auto alloc = [&](size_t bytes) {
    void* p = ws + off;
    off += (bytes + 255) & ~(size_t)255;
    return p;
  };
  u16* Abf = (u16*)alloc((size_t)NP * DIM * 2);
  u16* Bbf = (u16*)alloc((size_t)ML * DIM * 2);
  float* a2 = (float*)alloc(NP * 4);
  float* b2 = (float*)alloc(ML * 4);
  u64* packed = (u64*)alloc(NP * 8);
  u64* refined = (u64*)alloc(256 * 8);
  int* cand = (int*)alloc(257 * 4);
  int* scal_i = (int*)alloc(64);
  float* scal_f = (float*)alloc(64);
  u64* t3 = (u64*)alloc(2048 * 3 * 8);
  float* t1 = (float*)alloc(512 * 512 * 4);
  float* t2 = (float*)alloc(512 * 512 * 4);

  hipMemsetAsync(packed, 0xFF, NP * 8, stream);
  hipMemsetAsync(refined, 0xFF, 256 * 8, stream);

  prep_kernel<<<(NP + ML) / 4, 256, 0, stream>>>(patch, lib, Abf, Bbf, a2, b2);
  gemm_min_kernel<<<16384, 256, 0, stream>>>(Abf, Bbf, a2, b2, packed);
  cand_kernel<<<1, 256, 0, stream>>>(packed, cand);
  refine_kernel<<<2048, 256, 0, stream>>>(patch, lib, cand, refined);
  pick_kernel<<<1, 256, 0, stream>>>(refined, cand, scal_i, scal_f);
  wtop_kernel<<<2048, 256, 0, stream>>>(lib, scal_i, t3);
  final_kernel<<<1, 256, 0, stream>>>(t3, patch, lib, scal_i, scal_f, out);
  resize_kernel<<<1024, 256, 0, stream>>>(packed, t1);
  blurv_kernel<<<1024, 256, 0, stream>>>(t1, t2);
  blurh_kernel<<<1024, 256, 0, stream>>>(t2, out + 1);
}

// Round 6
// 335.876 us; speedup vs baseline: 5.4155x; 1.0790x over previous
//
#include <hip/hip_runtime.h>

#define NP 4096
#define DIM 384
#define ML 65536
#define INFF 3.402823466e38f

typedef short bf16x8 __attribute__((ext_vector_type(8)));
typedef float f32x4 __attribute__((ext_vector_type(4)));
typedef unsigned short u16;
typedef unsigned long long u64;

typedef __attribute__((address_space(1))) unsigned int as1_u32;
typedef __attribute__((address_space(3))) unsigned int as3_u32;

__device__ __forceinline__ void gl_lds16(const void* g, void* l) {
  __builtin_amdgcn_global_load_lds((const as1_u32*)g, (as3_u32*)l, 16, 0, 0);
}

__device__ __forceinline__ u16 f2bf(float x) {
  unsigned u = __float_as_uint(x);
  u += 0x7FFFu + ((u >> 16) & 1u);
  return (u16)(u >> 16);
}

// ---------------- prep: fp32 -> bf16 + row sumsq (wave per row, both inputs) ----------------
__global__ __launch_bounds__(256) void prep_kernel(const float* __restrict__ patch,
                                                   const float* __restrict__ lib,
                                                   u16* __restrict__ Abf,
                                                   u16* __restrict__ Bbf,
                                                   float* __restrict__ a2,
                                                   float* __restrict__ b2) {
  const int row = blockIdx.x * 4 + (threadIdx.x >> 6);
  const int lane = threadIdx.x & 63;
  const float* src;
  u16* dst;
  float* nrm;
  int r;
  if (row < NP) { src = patch; dst = Abf; nrm = a2; r = row; }
  else          { src = lib;   dst = Bbf; nrm = b2; r = row - NP; }
  float s = 0.f;
#pragma unroll
  for (int j = 0; j < 3; ++j) {
    const float2 v = *reinterpret_cast<const float2*>(src + (size_t)r * DIM + j * 128 + lane * 2);
    s += v.x * v.x + v.y * v.y;
    const unsigned p = ((unsigned)f2bf(v.y) << 16) | (unsigned)f2bf(v.x);
    *reinterpret_cast<unsigned*>(dst + (size_t)r * DIM + j * 128 + lane * 2) = p;
  }
#pragma unroll
  for (int m = 1; m < 64; m <<= 1) s += __shfl_xor(s, m);
  if (lane == 0) nrm[r] = s;
}

// ---- fused bf16 GEMM + row-min: 256x256 tile, 8 waves, BK=64, dbuf, T2+T1 ----
__global__ __launch_bounds__(512, 2) void gemm_min_kernel(const u16* __restrict__ Abf,
                                                          const u16* __restrict__ Bbf,
                                                          const float* __restrict__ a2,
                                                          const float* __restrict__ b2,
                                                          u64* __restrict__ packed) {
  __shared__ __align__(16) u16 As[2][16384];  // 64 KB
  __shared__ __align__(16) u16 Bs[2][16384];  // 64 KB
  const int tid = threadIdx.x;
  const int lane = tid & 63;
  const int w = tid >> 6;          // 0..7
  const int wm = w >> 2;           // 0..1  (patch half)
  const int wn = w & 3;            // 0..3  (lib quarter)
  const int cl = lane & 15, rg = lane >> 4;

  // XCD remap: nwg=4096. xt fastest (16 patch tiles), contiguous yt per XCD.
  const int orig = blockIdx.x;
  const int logical = (orig & 7) * 512 + (orig >> 3);
  const int xt = logical & 15;
  const int yt = logical >> 4;
  const int n0 = xt * 256;   // patch rows
  const int m0 = yt * 256;   // lib rows (output cols)

  // staging addresses (kt-invariant, advanced by +=64 per tile)
  const u16* ga[4]; const u16* gb[4]; int lof[4];
#pragma unroll
  for (int i = 0; i < 4; ++i) {
    const int P = i * 8192 + tid * 16;     // linear LDS dest byte in 32KB tile
    const int r = P >> 7;                  // tile row (128B per row), 0..255
    const int L = P ^ ((r & 7) << 4);      // inverse-swizzled source offset
    const int c = (L & 127) >> 1;          // ushort col within row
    lof[i] = P;
    ga[i] = Abf + (size_t)(n0 + r) * DIM + c;
    gb[i] = Bbf + (size_t)(m0 + r) * DIM + c;
  }

  // fragment byte offsets (kt-invariant)
  int offA[2][8], offB[2][4];
#pragma unroll
  for (int kk = 0; kk < 2; ++kk) {
#pragma unroll
    for (int j = 0; j < 8; ++j)
      offA[kk][j] = (((wm * 128 + j * 16 + cl) * 128) + kk * 64 + rg * 16) ^ ((cl & 7) << 4);
#pragma unroll
    for (int i = 0; i < 4; ++i)
      offB[kk][i] = (((wn * 64 + i * 16 + cl) * 128) + kk * 64 + rg * 16) ^ ((cl & 7) << 4);
  }

  f32x4 acc[4][8] = {};

  // prologue: stage tile 0 into buf 0
#pragma unroll
  for (int i = 0; i < 4; ++i) {
    gl_lds16(ga[i], (char*)As[0] + lof[i]);
    gl_lds16(gb[i], (char*)Bs[0] + lof[i]);
    ga[i] += 64; gb[i] += 64;
  }

#pragma unroll
  for (int kt = 0; kt < 6; ++kt) {
    const int buf = kt & 1;
    if (kt < 5) {
#pragma unroll
      for (int i = 0; i < 4; ++i) {
        gl_lds16(ga[i], (char*)As[buf ^ 1] + lof[i]);
        gl_lds16(gb[i], (char*)Bs[buf ^ 1] + lof[i]);
        ga[i] += 64; gb[i] += 64;
      }
      asm volatile("s_waitcnt vmcnt(8)" ::: "memory");  // tile kt landed; kt+1 in flight
    } else {
      asm volatile("s_waitcnt vmcnt(0)" ::: "memory");
    }
    __builtin_amdgcn_s_barrier();
    __builtin_amdgcn_sched_barrier(0);
#pragma unroll
    for (int kk = 0; kk < 2; ++kk) {
      bf16x8 af[8], bg[4];
#pragma unroll
      for (int j = 0; j < 8; ++j)
        af[j] = *reinterpret_cast<const bf16x8*>((const char*)As[buf] + offA[kk][j]);
#pragma unroll
      for (int i = 0; i < 4; ++i)
        bg[i] = *reinterpret_cast<const bf16x8*>((const char*)Bs[buf] + offB[kk][i]);
      // swapped operands: D[lib][patch] -> patch col = cl in C/D layout
#pragma unroll
      for (int i = 0; i < 4; ++i)
#pragma unroll
        for (int j = 0; j < 8; ++j)
          acc[i][j] = __builtin_amdgcn_mfma_f32_16x16x32_bf16(bg[i], af[j], acc[i][j], 0, 0, 0);
    }
    __builtin_amdgcn_s_barrier();
    __builtin_amdgcn_sched_barrier(0);
  }

  // epilogue: lane (cl,rg), frag (i,j), reg r holds dot for
  //   patch row = n0 + wm*128 + j*16 + cl ; lib col = m0 + wn*64 + i*16 + rg*4 + r
  const int colb = m0 + wn * 64 + rg * 4;
  float bc[4][4];
#pragma unroll
  for (int i = 0; i < 4; ++i)
#pragma unroll
    for (int r = 0; r < 4; ++r) bc[i][r] = b2[colb + i * 16 + r];

  u64* sh = reinterpret_cast<u64*>(As);  // 256 rows x 4 wn slots = 8KB scratch

#pragma unroll
  for (int j = 0; j < 8; ++j) {
    const int prow = wm * 128 + j * 16 + cl;
    const float ar = a2[n0 + prow];
    u64 best = ~0ull;
#pragma unroll
    for (int i = 0; i < 4; ++i)
#pragma unroll
      for (int r = 0; r < 4; ++r) {
        const float d2 = fmaxf(ar + bc[i][r] - 2.0f * acc[i][j][r], 0.0f);
        const u64 p = ((u64)__float_as_uint(d2) << 32) | (unsigned)(colb + i * 16 + r);
        best = p < best ? p : best;
      }
    const u64 o1 = __shfl_xor(best, 16); best = o1 < best ? o1 : best;
    const u64 o2 = __shfl_xor(best, 32); best = o2 < best ? o2 : best;
    if (rg == 0) sh[prow * 4 + wn] = best;
  }
  __syncthreads();
  if (tid < 256) {
    u64 v = sh[tid * 4];
#pragma unroll
    for (int k = 1; k < 4; ++k) { const u64 o = sh[tid * 4 + k]; v = o < v ? o : v; }
    atomicMin(&packed[n0 + tid], v);
  }
}

// ---------------- candidate rows near the max ----------------
__global__ __launch_bounds__(256) void cand_kernel(const u64* __restrict__ packed,
                                                   int* __restrict__ cand) {
  const int tid = threadIdx.x;
  float mx = -1.f;
  for (int n = tid; n < NP; n += 256) {
    const float v = __uint_as_float((unsigned)(packed[n] >> 32));
    mx = fmaxf(mx, v);
  }
#pragma unroll
  for (int m = 1; m < 64; m <<= 1) mx = fmaxf(mx, __shfl_xor(mx, m));
  __shared__ float wmax[4];
  __shared__ float smax;
  if ((tid & 63) == 0) wmax[tid >> 6] = mx;
  __syncthreads();
  if (tid == 0) {
    smax = fmaxf(fmaxf(wmax[0], wmax[1]), fmaxf(wmax[2], wmax[3]));
    cand[0] = 0;
  }
  __syncthreads();
  const float thr = smax - 4.0f;  // d^2 margin >> bf16 error
  for (int n = tid; n < NP; n += 256) {
    const float v = __uint_as_float((unsigned)(packed[n] >> 32));
    if (v >= thr) {
      const int slot = atomicAdd(&cand[0], 1);
      if (slot < 256) cand[1 + slot] = n;
    }
  }
}

// ---------------- exact fp32 refinement: block owns 32 lib rows ----------------
__global__ __launch_bounds__(256) void refine_kernel(const float* __restrict__ patch,
                                                     const float* __restrict__ lib,
                                                     const int* __restrict__ cand,
                                                     u64* __restrict__ refined) {
  const int cnt = min(cand[0], 256);
  const int tid = threadIdx.x, lane = tid & 63, w = tid >> 6;
  const int base = blockIdx.x * 32;  // 2048 blocks
  __shared__ float a[8][DIM];        // 12 KB candidate staging
  __shared__ u64 rb[8][4];

  for (int g0 = 0; g0 < cnt; g0 += 8) {
    const int gc = min(cnt - g0, 8);
    for (int i = tid; i < gc * DIM; i += 256) {
      const int c = i / DIM, e = i - c * DIM;
      a[c][e] = patch[(size_t)cand[1 + g0 + c] * DIM + e];
    }
    __syncthreads();

    u64 wbest[8];
#pragma unroll
    for (int c = 0; c < 8; ++c) wbest[c] = ~0ull;

    for (int it = 0; it < 8; ++it) {
      const int m = base + w * 8 + it;
      float lr[6];
#pragma unroll
      for (int j = 0; j < 3; ++j) {
        const float2 v = *reinterpret_cast<const float2*>(lib + (size_t)m * DIM + j * 128 + lane * 2);
        lr[j * 2] = v.x; lr[j * 2 + 1] = v.y;
      }
#pragma unroll
      for (int c = 0; c < 8; ++c) {
        if (c >= gc) break;
        float s = 0.f;
#pragma unroll
        for (int j = 0; j < 3; ++j) {
          const float d0 = lr[j * 2] - a[c][j * 128 + lane * 2];
          const float d1 = lr[j * 2 + 1] - a[c][j * 128 + lane * 2 + 1];
          s += d0 * d0 + d1 * d1;
        }
#pragma unroll
        for (int msk = 1; msk < 64; msk <<= 1) s += __shfl_xor(s, msk);
        const u64 p = ((u64)__float_as_uint(s) << 32) | (unsigned)m;
        wbest[c] = p < wbest[c] ? p : wbest[c];
      }
    }
    if (lane == 0) {
#pragma unroll
      for (int c = 0; c < 8; ++c)
        if (c < gc) rb[c][w] = wbest[c];
    }
    __syncthreads();
    if (tid < gc) {
      u64 b = rb[tid][0];
#pragma unroll
      for (int k = 1; k < 4; ++k) b = rb[tid][k] < b ? rb[tid][k] : b;
      atomicMin(&refined[g0 + tid], b);
    }
    __syncthreads();
  }
}

// ---------------- pick exact argmax row ----------------
__global__ __launch_bounds__(256) void pick_kernel(const u64* __restrict__ refined,
                                                   const int* __restrict__ cand,
                                                   int* __restrict__ scal_i,
                                                   float* __restrict__ scal_f) {
  const int tid = threadIdx.x, lane = tid & 63, w = tid >> 6;
  const int cnt = min(cand[0], 256);
  float v = -1.f;
  int nrow = 0x7FFFFFFF;
  int mi = 0;
  if (tid < cnt) {
    const u64 p = refined[tid];
    v = __uint_as_float((unsigned)(p >> 32));
    nrow = cand[1 + tid];
    mi = (int)(unsigned)p;
  }
#pragma unroll
  for (int msk = 1; msk < 64; msk <<= 1) {
    const float ov = __shfl_xor(v, msk);
    const int on = __shfl_xor(nrow, msk);
    const int om = __shfl_xor(mi, msk);
    if (ov > v || (ov == v && on < nrow)) { v = ov; nrow = on; mi = om; }
  }
  __shared__ float sv[4]; __shared__ int sn[4]; __shared__ int sm[4];
  if (lane == 0) { sv[w] = v; sn[w] = nrow; sm[w] = mi; }
  __syncthreads();
  if (tid == 0) {
    for (int k = 1; k < 4; ++k)
      if (sv[k] > v || (sv[k] == v && sn[k] < nrow)) { v = sv[k]; nrow = sn[k]; mi = sm[k]; }
    scal_i[0] = nrow;       // s_idx
    scal_i[1] = mi;         // m_star index
    scal_f[0] = sqrtf(fmaxf(v, 0.f));  // s_star
  }
}

// ---------------- fused w_dist + per-block top-3 (block owns 32 rows) ----------------
__device__ __forceinline__ void ins3u(u64 x, u64* v) {
  if (x < v[2]) {
    v[2] = x;
    if (v[2] < v[1]) { u64 t = v[1]; v[1] = v[2]; v[2] = t; }
    if (v[1] < v[0]) { u64 t = v[0]; v[0] = v[1]; v[1] = t; }
  }
}

__global__ __launch_bounds__(256) void wtop_kernel(const float* __restrict__ lib,
                                                   const int* __restrict__ scal_i,
                                                   u64* __restrict__ t3) {
  __shared__ float a[DIM];
  __shared__ u64 sv[12];
  const int tid = threadIdx.x, lane = tid & 63, w = tid >> 6;
  const int ms = scal_i[1];
  for (int i = tid; i < DIM; i += 256) a[i] = lib[(size_t)ms * DIM + i];
  __syncthreads();
  const int base = blockIdx.x * 32;  // 2048 blocks
  u64 v[3] = {~0ull, ~0ull, ~0ull};
  for (int it = 0; it < 8; ++it) {
    const int m = base + w * 8 + it;
    float s = 0.f;
#pragma unroll
    for (int j = 0; j < 3; ++j) {
      const float2 lv = *reinterpret_cast<const float2*>(lib + (size_t)m * DIM + j * 128 + lane * 2);
      const float d0 = lv.x - a[j * 128 + lane * 2];
      const float d1 = lv.y - a[j * 128 + lane * 2 + 1];
      s += d0 * d0 + d1 * d1;
    }
#pragma unroll
    for (int msk = 1; msk < 64; msk <<= 1) s += __shfl_xor(s, msk);
    ins3u(((u64)__float_as_uint(s) << 32) | (unsigned)m, v);  // wave-uniform
  }
  if (lane == 0) {
#pragma unroll
    for (int k = 0; k < 3; ++k) sv[w * 3 + k] = v[k];
  }
  __syncthreads();
  if (tid == 0) {
    u64 fv[3] = {~0ull, ~0ull, ~0ull};
    for (int k = 0; k < 12; ++k) ins3u(sv[k], fv);
#pragma unroll
    for (int k = 0; k < 3; ++k) t3[blockIdx.x * 3 + k] = fv[k];
  }
}

// ---------------- stage-2 top-3 + final score ----------------
__global__ __launch_bounds__(256) void final_kernel(const u64* __restrict__ t3,
                                                    const float* __restrict__ patch,
                                                    const float* __restrict__ lib,
                                                    const int* __restrict__ scal_i,
                                                    const float* __restrict__ scal_f,
                                                    float* __restrict__ out) {
  const int tid = threadIdx.x, lane = tid & 63, w = tid >> 6;
  u64 v[3] = {~0ull, ~0ull, ~0ull};
  for (int i = tid; i < 6144; i += 256) ins3u(t3[i], v);
#pragma unroll
  for (int msk = 1; msk < 64; msk <<= 1) {
    u64 o0 = __shfl_xor(v[0], msk);
    u64 o1 = __shfl_xor(v[1], msk);
    u64 o2 = __shfl_xor(v[2], msk);
    ins3u(o0, v); ins3u(o1, v); ins3u(o2, v);
  }
  __shared__ u64 sv[12];
  __shared__ int nn[2]; __shared__ float kk[2];
  if (lane == 0) {
#pragma unroll
    for (int k = 0; k < 3; ++k) sv[w * 3 + k] = v[k];
  }
  __syncthreads();
  if (tid == 0) {
    u64 fv[3] = {~0ull, ~0ull, ~0ull};
    for (int k = 0; k < 12; ++k) ins3u(sv[k], fv);
    nn[0] = (int)(unsigned)fv[1];  // skip fv[0] == m_star itself
    nn[1] = (int)(unsigned)fv[2];
  }
  __syncthreads();
  if (w < 2) {
    const int s_idx = scal_i[0];
    const int nnx = nn[w];
    float s = 0.f;
#pragma unroll
    for (int k = 0; k < 6; ++k) {
      const float d = patch[(size_t)s_idx * DIM + lane + k * 64] - lib[(size_t)nnx * DIM + lane + k * 64];
      s += d * d;
    }
#pragma unroll
    for (int msk = 1; msk < 64; msk <<= 1) s += __shfl_xor(s, msk);
    if (lane == 0) kk[w] = sqrtf(s);
  }
  __syncthreads();
  if (tid == 0) {
    const float s_star = scal_f[0];
    const float Ds = 19.59591794f;  // sqrt(384)
    const float wt = 1.0f - expf(s_star / Ds) / (expf(kk[0] / Ds) + expf(kk[1] / Ds));
    out[0] = wt * s_star;
  }
}

// ---------------- score map: resize (reads packed directly) + blur ----------------
__device__ __forceinline__ float mval(const u64* packed, int n) {
  return sqrtf(fmaxf(__uint_as_float((unsigned)(packed[n] >> 32)), 0.f));
}

__global__ __launch_bounds__(256) void resize_kernel(const u64* __restrict__ packed,
                                                     float* __restrict__ t1) {
  const int idx = blockIdx.x * 256 + threadIdx.x;  // 262144
  const int x = idx & 511, y = idx >> 9;
  const float sy = y * 0.125f - 0.4375f;
  const float sx = x * 0.125f - 0.4375f;
  const int y0 = (int)floorf(sy); const float fy = sy - (float)y0;
  const int x0 = (int)floorf(sx); const float fx = sx - (float)x0;
  const int ya = max(y0, 0), yb = min(y0 + 1, 63);
  const int xa = max(x0, 0), xb = min(x0 + 1, 63);
  const float v00 = mval(packed, ya * 64 + xa), v01 = mval(packed, ya * 64 + xb);
  const float v10 = mval(packed, yb * 64 + xa), v11 = mval(packed, yb * 64 + xb);
  t1[idx] = (1.f - fy) * ((1.f - fx) * v00 + fx * v01) + fy * ((1.f - fx) * v10 + fx * v11);
}

__device__ __constant__ float BW[9] = {
    0.0816741424f, 0.1016453893f, 0.1188358540f, 0.1305155396f, 0.1346581512f,
    0.1305155396f, 0.1188358540f, 0.1016453893f, 0.0816741424f};

__global__ __launch_bounds__(256) void blurv_kernel(const float* __restrict__ t1,
                                                    float* __restrict__ t2) {
  const int idx = blockIdx.x * 256 + threadIdx.x;
  const int x = idx & 511, y = idx >> 9;
  float s = 0.f;
#pragma unroll
  for (int k = -4; k <= 4; ++k) {
    const int yy = y + k;
    if (yy >= 0 && yy < 512) s += BW[k + 4] * t1[yy * 512 + x];
  }
  t2[idx] = s;
}

__global__ __launch_bounds__(256) void blurh_kernel(const float* __restrict__ t2,
                                                    float* __restrict__ out) {
  const int idx = blockIdx.x * 256 + threadIdx.x;
  const int x = idx & 511, y = idx >> 9;
  float s = 0.f;
#pragma unroll
  for (int k = -4; k <= 4; ++k) {
    const int xx = x + k;
    if (xx >= 0 && xx < 512) s += BW[k + 4] * t2[y * 512 + xx];
  }
  out[idx] = s;
}

extern "C" void kernel_launch(void* const* d_in, const int* in_sizes, int n_in,
                              void* d_out, int out_size, void* d_ws, size_t ws_size,
                              hipStream_t stream) {
  const float* patch = (const float*)d_in[0];
  const float* lib = (const float*)d_in[1];
  float* out = (float*)d_out;

  char* ws = (char*)d_ws;
  size_t off = 0;
  auto alloc = [&](size_t bytes) {
    void* p = ws + off;
    off += (bytes + 255) & ~(size_t)255;
    return p;
  };
  u16* Abf = (u16*)alloc((size_t)NP * DIM * 2);
  u16* Bbf = (u16*)alloc((size_t)ML * DIM * 2);
  float* a2 = (float*)alloc(NP * 4);
  float* b2 = (float*)alloc(ML * 4);
  u64* packed = (u64*)alloc(NP * 8);
  u64* refined = (u64*)alloc(256 * 8);
  int* cand = (int*)alloc(257 * 4);
  int* scal_i = (int*)alloc(64);
  float* scal_f = (float*)alloc(64);
  u64* t3 = (u64*)alloc(2048 * 3 * 8);
  float* t1 = (float*)alloc(512 * 512 * 4);
  float* t2 = (float*)alloc(512 * 512 * 4);

  hipMemsetAsync(packed, 0xFF, NP * 8, stream);
  hipMemsetAsync(refined, 0xFF, 256 * 8, stream);

  prep_kernel<<<(NP + ML) / 4, 256, 0, stream>>>(patch, lib, Abf, Bbf, a2, b2);
  gemm_min_kernel<<<4096, 512, 0, stream>>>(Abf, Bbf, a2, b2, packed);
  cand_kernel<<<1, 256, 0, stream>>>(packed, cand);
  refine_kernel<<<2048, 256, 0, stream>>>(patch, lib, cand, refined);
  pick_kernel<<<1, 256, 0, stream>>>(refined, cand, scal_i, scal_f);
  wtop_kernel<<<2048, 256, 0, stream>>>(lib, scal_i, t3);
  final_kernel<<<1, 256, 0, stream>>>(t3, patch, lib, scal_i, scal_f, out);
  resize_kernel<<<1024, 256, 0, stream>>>(packed, t1);
  blurv_kernel<<<1024, 256, 0, stream>>>(t1, t2);
  blurh_kernel<<<1024, 256, 0, stream>>>(t2, out + 1);
}